// Round 2
// baseline (325.389 us; speedup 1.0000x reference)
//
#include <hip/hip_runtime.h>
#include <math.h>

// GLA: B=2, N=1024, D=1024, H=4, KD=512, VD=1024, DK=128, DV=256, LR=16
// Round 14: launch-count attack. 9 kernels -> 4:
//   1) prep_lowrank_k : weight transpose/cvt + x->bf16 + xl=x@Wgk1 (+ zero barriers)
//   2) proj_mfma_k    : unchanged round-13 (gld16 + XOR swizzle, 128x128)
//   3) fused_scan_k   : gate_scan -> [gridbar] -> intra_kv -> [gridbar] ->
//                       state_scan -> [gridbar] -> o_inter  (256 blocks, co-resident,
//                       device-scope atomic barriers; Qs LDS tile reused across phases)
//   4) fused_out_k    : norm_gate (wave-per-group) -> [gridbar] -> out GEMM
// All phase math identical to round 13 (same accumulation order). Workspace ~37 MB + bar.

typedef __attribute__((ext_vector_type(4))) float vf4;
typedef __attribute__((ext_vector_type(4))) unsigned int vu4;
typedef __attribute__((ext_vector_type(8))) short short8;
typedef __attribute__((ext_vector_type(4))) unsigned short us4;

#define DEVI static __device__ __forceinline__
DEVI vf4 vzero() { vf4 x = {0.f, 0.f, 0.f, 0.f}; return x; }

DEVI float bf2f(unsigned int u) {
  union { unsigned int i; float f; } c; c.i = u << 16; return c.f;
}
DEVI unsigned short f2bf(float f) {
  union { float f; unsigned int i; } c; c.f = f;
  unsigned int i = c.i;
  return (unsigned short)((i + 0x7fffu + ((i >> 16) & 1u)) >> 16);
}
DEVI void unpack8(vu4 r, float* f) {
  f[0] = bf2f(r.x & 0xffffu); f[1] = bf2f(r.x >> 16);
  f[2] = bf2f(r.y & 0xffffu); f[3] = bf2f(r.y >> 16);
  f[4] = bf2f(r.z & 0xffffu); f[5] = bf2f(r.z >> 16);
  f[6] = bf2f(r.w & 0xffffu); f[7] = bf2f(r.w >> 16);
}
DEVI vu4 pack8(const float* f) {
  vu4 o;
  o.x = (unsigned int)f2bf(f[0]) | ((unsigned int)f2bf(f[1]) << 16);
  o.y = (unsigned int)f2bf(f[2]) | ((unsigned int)f2bf(f[3]) << 16);
  o.z = (unsigned int)f2bf(f[4]) | ((unsigned int)f2bf(f[5]) << 16);
  o.w = (unsigned int)f2bf(f[6]) | ((unsigned int)f2bf(f[7]) << 16);
  return o;
}

DEVI void gld16(const unsigned short* g, unsigned short* l) {
  __builtin_amdgcn_global_load_lds(
      (const __attribute__((address_space(1))) unsigned int*)g,
      (__attribute__((address_space(3))) unsigned int*)l,
      16, 0, 0);
}

// Device-scope grid barrier. Safe: grid=256 blocks, <=2 blocks/CU by LDS ->
// all blocks resident (capacity 256 CU x >=1 block). Counters zeroed by
// prep_lowrank_k (previous kernel on same stream).
DEVI void gridbar(unsigned* c, unsigned tgt) {
  __syncthreads();
  if (threadIdx.x == 0) {
    __threadfence();  // release: make this block's writes device-visible
    __hip_atomic_fetch_add(c, 1u, __ATOMIC_ACQ_REL, __HIP_MEMORY_SCOPE_AGENT);
    while (__hip_atomic_load(c, __ATOMIC_ACQUIRE, __HIP_MEMORY_SCOPE_AGENT) < tgt)
      __builtin_amdgcn_s_sleep(1);
    __threadfence();  // acquire: invalidate stale L1/L2 before data reads
  }
  __syncthreads();
}

// ---------------------------------------------------------------------------
// prep + lowrank fused. grid 2048 blocks x 256.
//   bid <  1536 : prep (ct = bid%96, kt = bid/96)
//   bid >= 1536 : lowrank, wave w handles row (bid-1536)*4 + w
// ---------------------------------------------------------------------------
__global__ __launch_bounds__(256)
void prep_lowrank_k(const float* __restrict__ Wq, const float* __restrict__ Wk,
                    const float* __restrict__ Wv, const float* __restrict__ Wg,
                    const float* __restrict__ Wo, const float* __restrict__ X,
                    const float* __restrict__ Wgk1,
                    unsigned short* __restrict__ wqT, unsigned short* __restrict__ wkT,
                    unsigned short* __restrict__ wvT, unsigned short* __restrict__ wgT,
                    unsigned short* __restrict__ woT, unsigned short* __restrict__ xb,
                    float* __restrict__ xl, unsigned* __restrict__ bar) {
  __shared__ float T[64][65];
  const int bid = blockIdx.x;
  const int t = threadIdx.x;
  if (bid == 0 && t < 8) bar[t] = 0;

  if (bid >= 1536) {  // ---- lowrank: xl = x @ Wgk1, one wave per row
    const int w = t >> 6, lane = t & 63;
    const int row = (bid - 1536) * 4 + w;
    float acc[16];
#pragma unroll
    for (int c2 = 0; c2 < 16; ++c2) acc[c2] = 0.f;
    const float* xp = X + (size_t)row * 1024 + lane * 16;
    float xv[16];
#pragma unroll
    for (int u = 0; u < 4; ++u)
      *(vf4*)&xv[u * 4] = *(const vf4*)(xp + u * 4);
#pragma unroll
    for (int j = 0; j < 16; ++j) {
      const float* wp = Wgk1 + (size_t)(lane * 16 + j) * 16;
      float wv[16];
#pragma unroll
      for (int u = 0; u < 4; ++u)
        *(vf4*)&wv[u * 4] = *(const vf4*)(wp + u * 4);
#pragma unroll
      for (int c2 = 0; c2 < 16; ++c2) acc[c2] = fmaf(xv[j], wv[c2], acc[c2]);
    }
#pragma unroll
    for (int mm = 1; mm < 64; mm <<= 1) {
#pragma unroll
      for (int c2 = 0; c2 < 16; ++c2) acc[c2] += __shfl_xor(acc[c2], mm, 64);
    }
    if (lane == 0) {
#pragma unroll
      for (int c2 = 0; c2 < 16; ++c2) xl[(size_t)row * 16 + c2] = acc[c2];
    }
    return;
  }

  const int ct = bid % 96, kt = bid / 96;
  const int r = t >> 2, s = t & 3;
  if (ct >= 64) {  // ---- x fp32 -> bf16
    const int rt = ct - 64;
    const size_t base = (size_t)(rt * 64 + r) * 1024 + kt * 64 + s * 16;
    float f[16];
    *(vf4*)&f[0]  = *(const vf4*)(X + base);
    *(vf4*)&f[4]  = *(const vf4*)(X + base + 4);
    *(vf4*)&f[8]  = *(const vf4*)(X + base + 8);
    *(vf4*)&f[12] = *(const vf4*)(X + base + 12);
    *(vu4*)(xb + base) = pack8(f);
    *(vu4*)(xb + base + 8) = pack8(f + 8);
    return;
  }
  const float* W; unsigned short* O; int N; int cb;
  if (ct < 8)       { W = Wq; O = wqT; N = 512;  cb = ct; }
  else if (ct < 16) { W = Wk; O = wkT; N = 512;  cb = ct - 8; }
  else if (ct < 32) { W = Wv; O = wvT; N = 1024; cb = ct - 16; }
  else if (ct < 48) { W = Wg; O = wgT; N = 1024; cb = ct - 32; }
  else              { W = Wo; O = woT; N = 1024; cb = ct - 48; }
  const float* src = W + (size_t)(kt * 64 + r) * N + cb * 64 + s * 16;
#pragma unroll
  for (int u = 0; u < 4; ++u) {
    vf4 v4 = *(const vf4*)(src + u * 4);
    T[r][s * 16 + u * 4 + 0] = v4.x;
    T[r][s * 16 + u * 4 + 1] = v4.y;
    T[r][s * 16 + u * 4 + 2] = v4.z;
    T[r][s * 16 + u * 4 + 3] = v4.w;
  }
  __syncthreads();
  unsigned int pk[8];
#pragma unroll
  for (int u = 0; u < 8; ++u) {
    unsigned int lo = f2bf(T[s * 16 + 2 * u][r]);
    unsigned int hi = f2bf(T[s * 16 + 2 * u + 1][r]);
    pk[u] = lo | (hi << 16);
  }
  unsigned short* dst = O + (size_t)(cb * 64 + r) * 1024 + kt * 64 + s * 16;
  *(vu4*)dst = *(vu4*)&pk[0];
  *(vu4*)(dst + 8) = *(vu4*)&pk[4];
}

// ---------------------------------------------------------------------------
// MFMA projection (round-13, unchanged): 128x128 tile, BK=64, gld16 staging,
// XOR-swizzled linear LDS. grid (24,16) = 384 blocks.
// ---------------------------------------------------------------------------
__global__ __launch_bounds__(256)
void proj_mfma_k(const unsigned short* __restrict__ xb,
                 const unsigned short* __restrict__ wqT, const unsigned short* __restrict__ wkT,
                 const unsigned short* __restrict__ wvT, const unsigned short* __restrict__ wgT,
                 unsigned short* __restrict__ qb, unsigned short* __restrict__ kb,
                 unsigned short* __restrict__ vb, unsigned short* __restrict__ sgb) {
  __shared__ __align__(16) unsigned short As[128 * 64];
  __shared__ __align__(16) unsigned short Bs[128 * 64];
  const int t = threadIdx.x;
  const int m0 = blockIdx.y << 7;
  const int nt = blockIdx.x;
  const unsigned short* WT; int n0; int kind;
  if (nt < 4)       { WT = wqT; n0 = nt << 7;        kind = 0; }
  else if (nt < 8)  { WT = wkT; n0 = (nt - 4) << 7;  kind = 1; }
  else if (nt < 16) { WT = wvT; n0 = (nt - 8) << 7;  kind = 2; }
  else              { WT = wgT; n0 = (nt - 16) << 7; kind = 3; }

  const int w = t >> 6, lane = t & 63;
  const int wm = (w >> 1) << 6, wn = (w & 1) << 6;
  const int qd = lane >> 4, m = lane & 15;
  const int srow = lane >> 3;
  const int scol = ((lane & 7) ^ srow) << 3;

  vf4 acc[4][4];
#pragma unroll
  for (int i = 0; i < 4; ++i)
#pragma unroll
    for (int j = 0; j < 4; ++j) acc[i][j] = vzero();

  for (int k0 = 0; k0 < 1024; k0 += 64) {
    __syncthreads();
#pragma unroll
    for (int cc = 0; cc < 4; ++cc) {
      const int c = (w << 2) + cc;
      const int row = (c << 3) + srow;
      gld16(xb + (size_t)(m0 + row) * 1024 + k0 + scol, (unsigned short*)As + (c << 9));
      gld16(WT + (size_t)(n0 + row) * 1024 + k0 + scol, (unsigned short*)Bs + (c << 9));
    }
    __syncthreads();
#pragma unroll
    for (int ks = 0; ks < 2; ++ks) {
      const int sw = (((ks << 2) + qd) ^ (m & 7)) << 3;
      short8 af[4], bf[4];
#pragma unroll
      for (int i = 0; i < 4; ++i)
        af[i] = *(const short8*)&As[(wm + i * 16 + m) * 64 + sw];
#pragma unroll
      for (int j = 0; j < 4; ++j)
        bf[j] = *(const short8*)&Bs[(wn + j * 16 + m) * 64 + sw];
#pragma unroll
      for (int i = 0; i < 4; ++i)
#pragma unroll
        for (int j = 0; j < 4; ++j)
          acc[i][j] = __builtin_amdgcn_mfma_f32_16x16x32_bf16(af[i], bf[j], acc[i][j], 0, 0, 0);
    }
  }
#pragma unroll
  for (int i = 0; i < 4; ++i) {
#pragma unroll
    for (int j = 0; j < 4; ++j) {
#pragma unroll
      for (int r = 0; r < 4; ++r) {
        const int grow = m0 + wm + i * 16 + qd * 4 + r;
        const int gcol = n0 + wn + j * 16 + m;
        float val = acc[i][j][r];
        if (kind == 0)      qb[(size_t)grow * 512 + gcol] = f2bf(val);
        else if (kind == 1) kb[(size_t)grow * 512 + gcol] = f2bf(val);
        else if (kind == 2) vb[(size_t)grow * 1024 + gcol] = f2bf(val);
        else {
          val = val / (1.f + expf(-val));
          sgb[(size_t)grow * 1024 + gcol] = f2bf(val);
        }
      }
    }
  }
}

// ---------------------------------------------------------------------------
// Fused scan path: gate -> intra_kv -> state_scan -> o_inter.
// grid 256 blocks x 256. LDS 76.5 KB (union; Ss overlays Ks+Kt; Qs reused).
// ---------------------------------------------------------------------------
__global__ __launch_bounds__(256)
void fused_scan_k(const float* __restrict__ xl, const float* __restrict__ W2,
                  const float* __restrict__ bias,
                  unsigned short* __restrict__ q16, unsigned short* __restrict__ k16,
                  float* __restrict__ ebtot, const unsigned short* __restrict__ v,
                  float* __restrict__ o, unsigned short* __restrict__ ST,
                  unsigned* __restrict__ bar) {
  __shared__ __align__(16) unsigned short L[39168];
  unsigned short* Qs  = L;            // 64*136
  unsigned short* Ks  = L + 8704;     // 64*136
  unsigned short* Kt  = L + 17408;    // 128*68
  unsigned short* Vt  = L + 26112;    // 128*68
  unsigned short* Asb = L + 34816;    // 64*68
  unsigned short* Ss  = L + 8704;     // 128*136 (overlays Ks+Kt, phase O only)

  const int t = threadIdx.x;
  const int bid = blockIdx.x;
  const int w = t >> 6, lane = t & 63;
  const int qd = lane >> 4, m = lane & 15;

  // ======== phase G: gate scan (RMW q,k; write ebtot) ========
  {
    const int wid = bid * 4 + w;            // 0..1023
    const int kt = wid & 31;
    const int c = (wid >> 5) & 15;
    const int b = wid >> 9;
    const int kbase = kt * 16;
    const size_t rowbase = (size_t)b * 1024 + c * 64;

    const float* xp = xl + (rowbase + lane) * 16;
    float xv[16];
#pragma unroll
    for (int u = 0; u < 4; ++u)
      *(vf4*)&xv[u * 4] = *(const vf4*)(xp + u * 4);

    const size_t a = (rowbase + lane) * 512 + kbase;
    vu4 qr0 = *(const vu4*)(q16 + a), qr1 = *(const vu4*)(q16 + a + 8);
    vu4 kr0 = *(const vu4*)(k16 + a), kr1 = *(const vu4*)(k16 + a + 8);
    float qf[16], kf[16];
    unpack8(qr0, qf); unpack8(qr1, qf + 8);
    unpack8(kr0, kf); unpack8(kr1, kf + 8);

    float gf[16];
#pragma unroll
    for (int cc = 0; cc < 16; ++cc) {
      const int col = kbase + cc;
      float z = bias[col];
#pragma unroll
      for (int j = 0; j < 16; ++j) z = fmaf(xv[j], W2[j * 512 + col], z);
      float ls = fminf(z, 0.f) - log1pf(expf(-fabsf(z)));
      float g = fmaxf(ls * (1.f / 16.f), -3.f);
#pragma unroll
      for (int d = 1; d < 64; d <<= 1) {
        float up = __shfl_up(g, d, 64);
        if (lane >= d) g += up;
      }
      qf[cc] *= expf(g);
      kf[cc] *= expf(fminf(-g, 80.f));
      gf[cc] = g;
    }
    *(vu4*)(q16 + a) = pack8(qf);
    *(vu4*)(q16 + a + 8) = pack8(qf + 8);
    *(vu4*)(k16 + a) = pack8(kf);
    *(vu4*)(k16 + a + 8) = pack8(kf + 8);
    if (lane == 63) {
      float* ep = ebtot + ((size_t)b * 16 + c) * 512 + kbase;
#pragma unroll
      for (int cc = 0; cc < 16; ++cc) ep[cc] = expf(gf[cc]);
    }
  }
  gridbar(bar + 0, 256);

  // ======== phase I: intra + kv ========
  const int vh = bid & 1, c = (bid >> 1) & 15, bh = bid >> 5;
  const int b = bh >> 2, h = bh & 3;
  const size_t rowbase = (size_t)b * 1024 + c * 64;
  {
#pragma unroll
    for (int u2 = 0; u2 < 4; ++u2) {
      const int id = t + (u2 << 8);
      const int row = id >> 4, kg = id & 15;
      vu4 rq = *(const vu4*)(q16 + (rowbase + row) * 512 + h * 128 + kg * 8);
      *(vu4*)&Qs[row * 136 + kg * 8] = rq;
      vu4 rk = *(const vu4*)(k16 + (rowbase + row) * 512 + h * 128 + kg * 8);
      *(vu4*)&Ks[row * 136 + kg * 8] = rk;
      const unsigned short* kp = (const unsigned short*)&rk;
#pragma unroll
      for (int u = 0; u < 8; ++u)
        Kt[(kg * 8 + u) * 68 + row] = kp[u];
      vu4 rv = *(const vu4*)(v + (rowbase + row) * 1024 + h * 256 + vh * 128 + kg * 8);
      const unsigned short* vp = (const unsigned short*)&rv;
#pragma unroll
      for (int u = 0; u < 8; ++u)
        Vt[(kg * 8 + u) * 68 + row] = vp[u];
    }
    __syncthreads();

    // phase 1: A = tril(Q K^T)
    {
      short8 af[4];
#pragma unroll
      for (int kf = 0; kf < 4; ++kf)
        af[kf] = *(const short8*)&Qs[(w * 16 + m) * 136 + kf * 32 + qd * 8];
      vf4 acc[4];
#pragma unroll
      for (int jt = 0; jt < 4; ++jt) acc[jt] = vzero();
#pragma unroll
      for (int jt = 0; jt < 4; ++jt)
#pragma unroll
        for (int kf = 0; kf < 4; ++kf) {
          short8 bfr = *(const short8*)&Ks[(jt * 16 + m) * 136 + kf * 32 + qd * 8];
          acc[jt] = __builtin_amdgcn_mfma_f32_16x16x32_bf16(af[kf], bfr, acc[jt], 0, 0, 0);
        }
#pragma unroll
      for (int jt = 0; jt < 4; ++jt)
#pragma unroll
        for (int r = 0; r < 4; ++r) {
          const int i = w * 16 + qd * 4 + r;
          const int j = jt * 16 + m;
          Asb[i * 68 + j] = f2bf((j <= i) ? acc[jt][r] : 0.f);
        }
    }
    __syncthreads();

    // phase 2: o_intra = A @ V
    {
      vf4 acc2[4][2];
#pragma unroll
      for (int mt = 0; mt < 4; ++mt) { acc2[mt][0] = vzero(); acc2[mt][1] = vzero(); }
#pragma unroll
      for (int kf = 0; kf < 2; ++kf) {
        short8 bf0 = *(const short8*)&Vt[(w * 32 + m) * 68 + kf * 32 + qd * 8];
        short8 bf1 = *(const short8*)&Vt[(w * 32 + 16 + m) * 68 + kf * 32 + qd * 8];
#pragma unroll
        for (int mt = 0; mt < 4; ++mt) {
          short8 af = *(const short8*)&Asb[(mt * 16 + m) * 68 + kf * 32 + qd * 8];
          acc2[mt][0] = __builtin_amdgcn_mfma_f32_16x16x32_bf16(af, bf0, acc2[mt][0], 0, 0, 0);
          acc2[mt][1] = __builtin_amdgcn_mfma_f32_16x16x32_bf16(af, bf1, acc2[mt][1], 0, 0, 0);
        }
      }
#pragma unroll
      for (int mt = 0; mt < 4; ++mt)
#pragma unroll
        for (int nt = 0; nt < 2; ++nt)
#pragma unroll
          for (int r = 0; r < 4; ++r) {
            const int i = mt * 16 + qd * 4 + r;
            const int vc = h * 256 + vh * 128 + w * 32 + nt * 16 + m;
            o[(rowbase + i) * 1024 + vc] = acc2[mt][nt][r];
          }
    }

    // phase 3: ST[v][k] = V^T @ K
    {
      short8 af3[2][2];
#pragma unroll
      for (int mt = 0; mt < 2; ++mt)
#pragma unroll
        for (int kf = 0; kf < 2; ++kf)
          af3[mt][kf] = *(const short8*)&Vt[(w * 32 + mt * 16 + m) * 68 + kf * 32 + qd * 8];
#pragma unroll
      for (int nt = 0; nt < 8; ++nt) {
        vf4 a0 = vzero(), a1 = vzero();
#pragma unroll
        for (int kf = 0; kf < 2; ++kf) {
          short8 bfr = *(const short8*)&Kt[(nt * 16 + m) * 68 + kf * 32 + qd * 8];
          a0 = __builtin_amdgcn_mfma_f32_16x16x32_bf16(af3[0][kf], bfr, a0, 0, 0, 0);
          a1 = __builtin_amdgcn_mfma_f32_16x16x32_bf16(af3[1][kf], bfr, a1, 0, 0, 0);
        }
        const size_t sbase = (size_t)(bh * 16 + c) * 256 + vh * 128 + w * 32;
#pragma unroll
        for (int r = 0; r < 4; ++r) {
          ST[(sbase + qd * 4 + r) * 128 + nt * 16 + m] = f2bf(a0[r]);
          ST[(sbase + 16 + qd * 4 + r) * 128 + nt * 16 + m] = f2bf(a1[r]);
        }
      }
    }
  }
  gridbar(bar + 1, 256);

  // ======== phase S: state scan (blocks 0..127) ========
  if (bid < 128) {
    const int idx = bid * 256 + t;          // 0..32767
    const int kg = idx & 15;
    const int vv = (idx >> 4) & 255;
    const int sbh = idx >> 12;
    const int sb = sbh >> 2, sh = sbh & 3;
    float s[8];
#pragma unroll
    for (int u = 0; u < 8; ++u) s[u] = 0.f;
    for (int sc = 0; sc < 16; ++sc) {
      unsigned short* p = ST + ((size_t)(sbh * 16 + sc) * 256 + vv) * 128 + kg * 8;
      const float* ep = ebtot + ((size_t)sb * 16 + sc) * 512 + sh * 128 + kg * 8;
      float e[8];
      *(vf4*)&e[0] = *(const vf4*)ep;
      *(vf4*)&e[4] = *(const vf4*)(ep + 4);
      float kv[8];
      unpack8(*(const vu4*)p, kv);
      *(vu4*)p = pack8(s);
#pragma unroll
      for (int u = 0; u < 8; ++u) s[u] = (s[u] + kv[u]) * e[u];
    }
  }
  gridbar(bar + 2, 256);

  // ======== phase O: o += Q~ @ S_c (Qs reused from phase I; Ss overlays Ks+Kt) ====
  {
#pragma unroll
    for (int u2 = 0; u2 < 8; ++u2) {
      const int id = t + (u2 << 8);
      const int vrow = id >> 4, kg = id & 15;
      *(vu4*)&Ss[vrow * 136 + kg * 8] =
          *(const vu4*)(ST + ((size_t)(bh * 16 + c) * 256 + vh * 128 + vrow) * 128 + kg * 8);
    }
    __syncthreads();

    short8 af[4];
#pragma unroll
    for (int kf = 0; kf < 4; ++kf)
      af[kf] = *(const short8*)&Qs[(w * 16 + m) * 136 + kf * 32 + qd * 8];
#pragma unroll
    for (int nt = 0; nt < 8; ++nt) {
      vf4 acc = vzero();
#pragma unroll
      for (int kf = 0; kf < 4; ++kf) {
        short8 bfr = *(const short8*)&Ss[(nt * 16 + m) * 136 + kf * 32 + qd * 8];
        acc = __builtin_amdgcn_mfma_f32_16x16x32_bf16(af[kf], bfr, acc, 0, 0, 0);
      }
      float* base = o + (rowbase + w * 16 + qd * 4) * 1024 + h * 256 + vh * 128 + nt * 16 + m;
#pragma unroll
      for (int r = 0; r < 4; ++r)
        base[(size_t)r * 1024] += acc[r];
    }
  }
}

// ---------------------------------------------------------------------------
// Fused epilogue: RMSNorm+silu-gate (wave-per-group) -> [gridbar] -> out GEMM.
// grid 256 blocks x 256.
// ---------------------------------------------------------------------------
__global__ __launch_bounds__(256)
void fused_out_k(const float* __restrict__ o, const float* __restrict__ rmsw,
                 const unsigned short* __restrict__ sg, unsigned short* __restrict__ ob,
                 const unsigned short* __restrict__ woT, float* __restrict__ Y,
                 unsigned* __restrict__ bar) {
  __shared__ __align__(16) unsigned short As[64 * 64];
  __shared__ __align__(16) unsigned short Bs[128 * 64];
  const int t = threadIdx.x;
  const int bid = blockIdx.x;
  const int w = t >> 6, lane = t & 63;

  // ======== phase N: norm + gate, one wave per (row, head) group, 8 per wave ===
#pragma unroll
  for (int g = 0; g < 8; ++g) {
    const int grp = (bid * 4 + w) * 8 + g;   // 0..8191
    const int row = grp >> 2, h = grp & 3;
    const size_t base = (size_t)row * 1024 + h * 256 + lane * 4;
    vf4 val = *(const vf4*)(o + base);
    float ss = val.x * val.x + val.y * val.y + val.z * val.z + val.w * val.w;
#pragma unroll
    for (int mm = 1; mm < 64; mm <<= 1) ss += __shfl_xor(ss, mm, 64);
    const float scale = rsqrtf(ss * (1.f / 256.f) + 1e-5f);
    us4 sgv = *(const us4*)(sg + base);
    vf4 rw = *(const vf4*)(rmsw + lane * 4);
    us4 outv;
    outv.x = f2bf(val.x * scale * rw.x * bf2f((unsigned int)sgv.x));
    outv.y = f2bf(val.y * scale * rw.y * bf2f((unsigned int)sgv.y));
    outv.z = f2bf(val.z * scale * rw.z * bf2f((unsigned int)sgv.z));
    outv.w = f2bf(val.w * scale * rw.w * bf2f((unsigned int)sgv.w));
    *(us4*)(ob + base) = outv;
  }
  gridbar(bar + 3, 256);

  // ======== phase Out: Y = ob @ woT (64x128 tile, gld16 + swizzle) ========
  const int m0 = (bid >> 3) << 6;
  const int n0 = (bid & 7) << 7;
  const int wm = (w >> 1) * 32, wn = (w & 1) * 64;
  const int qd = lane >> 4, m = lane & 15;
  const int srow = lane >> 3;
  const int scol = ((lane & 7) ^ srow) << 3;

  vf4 acc[2][4];
#pragma unroll
  for (int i = 0; i < 2; ++i)
#pragma unroll
    for (int j = 0; j < 4; ++j) acc[i][j] = vzero();

  for (int k0 = 0; k0 < 1024; k0 += 64) {
    __syncthreads();
#pragma unroll
    for (int cc = 0; cc < 2; ++cc) {
      const int c = (w << 1) + cc;
      const int row = (c << 3) + srow;
      gld16(ob + (size_t)(m0 + row) * 1024 + k0 + scol, (unsigned short*)As + (c << 9));
    }
#pragma unroll
    for (int cc = 0; cc < 4; ++cc) {
      const int c = (w << 2) + cc;
      const int row = (c << 3) + srow;
      gld16(woT + (size_t)(n0 + row) * 1024 + k0 + scol, (unsigned short*)Bs + (c << 9));
    }
    __syncthreads();
#pragma unroll
    for (int ks = 0; ks < 2; ++ks) {
      const int sw = (((ks << 2) + qd) ^ (m & 7)) << 3;
      short8 af[2], bf[4];
#pragma unroll
      for (int i = 0; i < 2; ++i)
        af[i] = *(const short8*)&As[(wm + i * 16 + m) * 64 + sw];
#pragma unroll
      for (int j = 0; j < 4; ++j)
        bf[j] = *(const short8*)&Bs[(wn + j * 16 + m) * 64 + sw];
#pragma unroll
      for (int i = 0; i < 2; ++i)
#pragma unroll
        for (int j = 0; j < 4; ++j)
          acc[i][j] = __builtin_amdgcn_mfma_f32_16x16x32_bf16(af[i], bf[j], acc[i][j], 0, 0, 0);
    }
  }
#pragma unroll
  for (int i = 0; i < 2; ++i)
#pragma unroll
    for (int j = 0; j < 4; ++j)
#pragma unroll
      for (int r = 0; r < 4; ++r) {
        const int grow = m0 + wm + i * 16 + qd * 4 + r;
        const int gcol = n0 + wn + j * 16 + m;
        Y[(size_t)grow * 1024 + gcol] = acc[i][j][r];
      }
}

// ---------------------------------------------------------------------------
extern "C" void kernel_launch(void* const* d_in, const int* in_sizes, int n_in,
                              void* d_out, int out_size, void* d_ws, size_t ws_size,
                              hipStream_t stream) {
  const float* x    = (const float*)d_in[0];
  const float* Wq   = (const float*)d_in[1];
  const float* Wk   = (const float*)d_in[2];
  const float* Wv   = (const float*)d_in[3];
  const float* Wg   = (const float*)d_in[4];
  const float* Wgk1 = (const float*)d_in[5];
  const float* Wgk2 = (const float*)d_in[6];
  const float* bgk2 = (const float*)d_in[7];
  const float* Wout = (const float*)d_in[8];
  const float* rmsw = (const float*)d_in[9];

  const size_t MB = 1u << 20;
  char* w = (char*)d_ws;
  unsigned short* qb16   = (unsigned short*)(w);           // [0,2) MB bf16
  unsigned short* kb16   = (unsigned short*)(w + 2 * MB);  // [2,4)
  unsigned short* vbuf   = (unsigned short*)(w + 4 * MB);  // [4,8)
  unsigned short* sgbuf  = (unsigned short*)(w + 8 * MB);  // [8,12)
  float*          obuf   = (float*)(w + 12 * MB);          // [12,20) fp32
  char*           sreg   = w + 20 * MB;                    // [20,28) multi-phase
  unsigned short* xb     = (unsigned short*)sreg;          //   phase 0: 4 MB
  unsigned short* STbuf  = (unsigned short*)sreg;          //   phase A: 8 MB [v][k]
  unsigned short* obuf_b = (unsigned short*)sreg;          //   phase B: 4 MB
  float*          xlbuf  = (float*)(w + 28 * MB);          // 128 KB
  float*          ebbuf  = (float*)(w + 28 * MB + 131072); // 64 KB
  unsigned short* wqT    = (unsigned short*)(w + 29 * MB); // 1 MB
  unsigned short* wkT    = (unsigned short*)(w + 30 * MB); // 1 MB
  unsigned short* wvT    = (unsigned short*)(w + 31 * MB); // 2 MB
  unsigned short* wgT    = (unsigned short*)(w + 33 * MB); // 2 MB
  unsigned short* woT    = (unsigned short*)(w + 35 * MB); // 2 MB
  unsigned*       bar    = (unsigned*)(w + 37 * MB);       // 32 B barrier counters

  prep_lowrank_k<<<2048, 256, 0, stream>>>(Wq, Wk, Wv, Wg, Wout, x, Wgk1,
                                           wqT, wkT, wvT, wgT, woT, xb, xlbuf, bar);
  proj_mfma_k<<<dim3(24, 16), 256, 0, stream>>>(xb, wqT, wkT, wvT, wgT, qb16, kb16, vbuf, sgbuf);
  fused_scan_k<<<256, 256, 0, stream>>>(xlbuf, Wgk2, bgk2, qb16, kb16, ebbuf, vbuf,
                                        obuf, STbuf, bar);
  fused_out_k<<<256, 256, 0, stream>>>(obuf, rmsw, sgbuf, obuf_b, woT, (float*)d_out, bar);
}

// Round 3
// 230.517 us; speedup vs baseline: 1.4116x; 1.4116x over previous
//
#include <hip/hip_runtime.h>
#include <math.h>

// GLA: B=2, N=1024, D=1024, H=4, KD=512, VD=1024, DK=128, DV=256, LR=16
// Round 15: barrier-free launch reduction. 9 -> 7 kernels:
//   1) prep_lowrank_k : weight transpose/cvt + x->bf16 + xl=x@Wgk1 (round-14, no bar)
//   2) proj_mfma_k    : round-13 unchanged (gld16 + XOR swizzle, 128x128)
//   3) intra_gate_k   : gate computed in-block (g scan -> EQ/EK factors in LDS),
//                       q/k gated at staging; writes ebtot; then intra+kv phases.
//                       q16/k16 stay RAW in global (no RMW kernel).
//   4) state_scan_k   : unchanged
//   5) o_inter_gate_k : recomputes q-gate factors in-block, gates Qs at staging
//   6) norm_gate_k    : vectorized wave-per-group (validated in round 14)
//   7) out_mfma_k     : round-13 unchanged
// Gate math identical op-order to old gate_scan_k -> bit-identical outputs.
// NO grid barriers (round-14 showed ~35 us per agent-scope barrier).

typedef __attribute__((ext_vector_type(4))) float vf4;
typedef __attribute__((ext_vector_type(4))) unsigned int vu4;
typedef __attribute__((ext_vector_type(8))) short short8;
typedef __attribute__((ext_vector_type(4))) unsigned short us4;

#define DEVI static __device__ __forceinline__
DEVI vf4 vzero() { vf4 x = {0.f, 0.f, 0.f, 0.f}; return x; }

DEVI float bf2f(unsigned int u) {
  union { unsigned int i; float f; } c; c.i = u << 16; return c.f;
}
DEVI unsigned short f2bf(float f) {
  union { float f; unsigned int i; } c; c.f = f;
  unsigned int i = c.i;
  return (unsigned short)((i + 0x7fffu + ((i >> 16) & 1u)) >> 16);
}
DEVI void unpack8(vu4 r, float* f) {
  f[0] = bf2f(r.x & 0xffffu); f[1] = bf2f(r.x >> 16);
  f[2] = bf2f(r.y & 0xffffu); f[3] = bf2f(r.y >> 16);
  f[4] = bf2f(r.z & 0xffffu); f[5] = bf2f(r.z >> 16);
  f[6] = bf2f(r.w & 0xffffu); f[7] = bf2f(r.w >> 16);
}
DEVI vu4 pack8(const float* f) {
  vu4 o;
  o.x = (unsigned int)f2bf(f[0]) | ((unsigned int)f2bf(f[1]) << 16);
  o.y = (unsigned int)f2bf(f[2]) | ((unsigned int)f2bf(f[3]) << 16);
  o.z = (unsigned int)f2bf(f[4]) | ((unsigned int)f2bf(f[5]) << 16);
  o.w = (unsigned int)f2bf(f[6]) | ((unsigned int)f2bf(f[7]) << 16);
  return o;
}

DEVI void gld16(const unsigned short* g, unsigned short* l) {
  __builtin_amdgcn_global_load_lds(
      (const __attribute__((address_space(1))) unsigned int*)g,
      (__attribute__((address_space(3))) unsigned int*)l,
      16, 0, 0);
}

// ---------------------------------------------------------------------------
// prep + lowrank fused. grid 2048 blocks x 256.
// ---------------------------------------------------------------------------
__global__ __launch_bounds__(256)
void prep_lowrank_k(const float* __restrict__ Wq, const float* __restrict__ Wk,
                    const float* __restrict__ Wv, const float* __restrict__ Wg,
                    const float* __restrict__ Wo, const float* __restrict__ X,
                    const float* __restrict__ Wgk1,
                    unsigned short* __restrict__ wqT, unsigned short* __restrict__ wkT,
                    unsigned short* __restrict__ wvT, unsigned short* __restrict__ wgT,
                    unsigned short* __restrict__ woT, unsigned short* __restrict__ xb,
                    float* __restrict__ xl) {
  __shared__ float T[64][65];
  const int bid = blockIdx.x;
  const int t = threadIdx.x;

  if (bid >= 1536) {  // ---- lowrank: xl = x @ Wgk1, one wave per row
    const int w = t >> 6, lane = t & 63;
    const int row = (bid - 1536) * 4 + w;
    float acc[16];
#pragma unroll
    for (int c2 = 0; c2 < 16; ++c2) acc[c2] = 0.f;
    const float* xp = X + (size_t)row * 1024 + lane * 16;
    float xv[16];
#pragma unroll
    for (int u = 0; u < 4; ++u)
      *(vf4*)&xv[u * 4] = *(const vf4*)(xp + u * 4);
#pragma unroll
    for (int j = 0; j < 16; ++j) {
      const float* wp = Wgk1 + (size_t)(lane * 16 + j) * 16;
      float wv[16];
#pragma unroll
      for (int u = 0; u < 4; ++u)
        *(vf4*)&wv[u * 4] = *(const vf4*)(wp + u * 4);
#pragma unroll
      for (int c2 = 0; c2 < 16; ++c2) acc[c2] = fmaf(xv[j], wv[c2], acc[c2]);
    }
#pragma unroll
    for (int mm = 1; mm < 64; mm <<= 1) {
#pragma unroll
      for (int c2 = 0; c2 < 16; ++c2) acc[c2] += __shfl_xor(acc[c2], mm, 64);
    }
    if (lane == 0) {
#pragma unroll
      for (int c2 = 0; c2 < 16; ++c2) xl[(size_t)row * 16 + c2] = acc[c2];
    }
    return;
  }

  const int ct = bid % 96, kt = bid / 96;
  const int r = t >> 2, s = t & 3;
  if (ct >= 64) {  // ---- x fp32 -> bf16
    const int rt = ct - 64;
    const size_t base = (size_t)(rt * 64 + r) * 1024 + kt * 64 + s * 16;
    float f[16];
    *(vf4*)&f[0]  = *(const vf4*)(X + base);
    *(vf4*)&f[4]  = *(const vf4*)(X + base + 4);
    *(vf4*)&f[8]  = *(const vf4*)(X + base + 8);
    *(vf4*)&f[12] = *(const vf4*)(X + base + 12);
    *(vu4*)(xb + base) = pack8(f);
    *(vu4*)(xb + base + 8) = pack8(f + 8);
    return;
  }
  const float* W; unsigned short* O; int N; int cb;
  if (ct < 8)       { W = Wq; O = wqT; N = 512;  cb = ct; }
  else if (ct < 16) { W = Wk; O = wkT; N = 512;  cb = ct - 8; }
  else if (ct < 32) { W = Wv; O = wvT; N = 1024; cb = ct - 16; }
  else if (ct < 48) { W = Wg; O = wgT; N = 1024; cb = ct - 32; }
  else              { W = Wo; O = woT; N = 1024; cb = ct - 48; }
  const float* src = W + (size_t)(kt * 64 + r) * N + cb * 64 + s * 16;
#pragma unroll
  for (int u = 0; u < 4; ++u) {
    vf4 v4 = *(const vf4*)(src + u * 4);
    T[r][s * 16 + u * 4 + 0] = v4.x;
    T[r][s * 16 + u * 4 + 1] = v4.y;
    T[r][s * 16 + u * 4 + 2] = v4.z;
    T[r][s * 16 + u * 4 + 3] = v4.w;
  }
  __syncthreads();
  unsigned int pk[8];
#pragma unroll
  for (int u = 0; u < 8; ++u) {
    unsigned int lo = f2bf(T[s * 16 + 2 * u][r]);
    unsigned int hi = f2bf(T[s * 16 + 2 * u + 1][r]);
    pk[u] = lo | (hi << 16);
  }
  unsigned short* dst = O + (size_t)(cb * 64 + r) * 1024 + kt * 64 + s * 16;
  *(vu4*)dst = *(vu4*)&pk[0];
  *(vu4*)(dst + 8) = *(vu4*)&pk[4];
}

// ---------------------------------------------------------------------------
// MFMA projection (round-13, unchanged). grid (24,16) = 384 blocks.
// ---------------------------------------------------------------------------
__global__ __launch_bounds__(256)
void proj_mfma_k(const unsigned short* __restrict__ xb,
                 const unsigned short* __restrict__ wqT, const unsigned short* __restrict__ wkT,
                 const unsigned short* __restrict__ wvT, const unsigned short* __restrict__ wgT,
                 unsigned short* __restrict__ qb, unsigned short* __restrict__ kb,
                 unsigned short* __restrict__ vb, unsigned short* __restrict__ sgb) {
  __shared__ __align__(16) unsigned short As[128 * 64];
  __shared__ __align__(16) unsigned short Bs[128 * 64];
  const int t = threadIdx.x;
  const int m0 = blockIdx.y << 7;
  const int nt = blockIdx.x;
  const unsigned short* WT; int n0; int kind;
  if (nt < 4)       { WT = wqT; n0 = nt << 7;        kind = 0; }
  else if (nt < 8)  { WT = wkT; n0 = (nt - 4) << 7;  kind = 1; }
  else if (nt < 16) { WT = wvT; n0 = (nt - 8) << 7;  kind = 2; }
  else              { WT = wgT; n0 = (nt - 16) << 7; kind = 3; }

  const int w = t >> 6, lane = t & 63;
  const int wm = (w >> 1) << 6, wn = (w & 1) << 6;
  const int qd = lane >> 4, m = lane & 15;
  const int srow = lane >> 3;
  const int scol = ((lane & 7) ^ srow) << 3;

  vf4 acc[4][4];
#pragma unroll
  for (int i = 0; i < 4; ++i)
#pragma unroll
    for (int j = 0; j < 4; ++j) acc[i][j] = vzero();

  for (int k0 = 0; k0 < 1024; k0 += 64) {
    __syncthreads();
#pragma unroll
    for (int cc = 0; cc < 4; ++cc) {
      const int c = (w << 2) + cc;
      const int row = (c << 3) + srow;
      gld16(xb + (size_t)(m0 + row) * 1024 + k0 + scol, (unsigned short*)As + (c << 9));
      gld16(WT + (size_t)(n0 + row) * 1024 + k0 + scol, (unsigned short*)Bs + (c << 9));
    }
    __syncthreads();
#pragma unroll
    for (int ks = 0; ks < 2; ++ks) {
      const int sw = (((ks << 2) + qd) ^ (m & 7)) << 3;
      short8 af[4], bf[4];
#pragma unroll
      for (int i = 0; i < 4; ++i)
        af[i] = *(const short8*)&As[(wm + i * 16 + m) * 64 + sw];
#pragma unroll
      for (int j = 0; j < 4; ++j)
        bf[j] = *(const short8*)&Bs[(wn + j * 16 + m) * 64 + sw];
#pragma unroll
      for (int i = 0; i < 4; ++i)
#pragma unroll
        for (int j = 0; j < 4; ++j)
          acc[i][j] = __builtin_amdgcn_mfma_f32_16x16x32_bf16(af[i], bf[j], acc[i][j], 0, 0, 0);
    }
  }
#pragma unroll
  for (int i = 0; i < 4; ++i) {
#pragma unroll
    for (int j = 0; j < 4; ++j) {
#pragma unroll
      for (int r = 0; r < 4; ++r) {
        const int grow = m0 + wm + i * 16 + qd * 4 + r;
        const int gcol = n0 + wn + j * 16 + m;
        float val = acc[i][j][r];
        if (kind == 0)      qb[(size_t)grow * 512 + gcol] = f2bf(val);
        else if (kind == 1) kb[(size_t)grow * 512 + gcol] = f2bf(val);
        else if (kind == 2) vb[(size_t)grow * 1024 + gcol] = f2bf(val);
        else {
          val = val / (1.f + expf(-val));
          sgb[(size_t)grow * 1024 + gcol] = f2bf(val);
        }
      }
    }
  }
}

// ---------------------------------------------------------------------------
// intra + kv with in-block gating. grid (vh2, chunk16, bh8) = 256 blocks.
// LDS: 78336 (tiles) + 2*33280 (EQ/EK [128][65] fp32) = 144896 B.
// ---------------------------------------------------------------------------
__global__ __launch_bounds__(256)
void intra_gate_k(const float* __restrict__ xl, const float* __restrict__ W2,
                  const float* __restrict__ bias,
                  const unsigned short* __restrict__ q16, const unsigned short* __restrict__ k16,
                  const unsigned short* __restrict__ v, float* __restrict__ o,
                  unsigned short* __restrict__ ST, float* __restrict__ ebtot) {
  __shared__ __align__(16) unsigned short Qs[64 * 136];
  __shared__ __align__(16) unsigned short Ks[64 * 136];
  __shared__ __align__(16) unsigned short Kt[128 * 68];
  __shared__ __align__(16) unsigned short Vt[128 * 68];
  __shared__ __align__(16) unsigned short Asb[64 * 68];
  __shared__ float EQ[128 * 65];   // [col_local][row] : expf(g)
  __shared__ float EK[128 * 65];   // [col_local][row] : expf(min(-g,80))
  const int t = threadIdx.x;
  const int vh = blockIdx.x, c = blockIdx.y, bh = blockIdx.z;
  const int b = bh >> 2, h = bh & 3;
  const size_t rowbase = (size_t)b * 1024 + c * 64;
  const int w = t >> 6, lane = t & 63;
  const int qd = lane >> 4, m = lane & 15;

  // ---- gate phase: g scan per column (identical op order to old gate_scan)
  {
    const float* xp = xl + (rowbase + lane) * 16;
    float xv[16];
#pragma unroll
    for (int u = 0; u < 4; ++u)
      *(vf4*)&xv[u * 4] = *(const vf4*)(xp + u * 4);
#pragma unroll
    for (int cc = 0; cc < 32; ++cc) {
      const int cl = w * 32 + cc;          // local col 0..127
      const int col = h * 128 + cl;        // global col (wave-uniform)
      float z = bias[col];
#pragma unroll
      for (int j = 0; j < 16; ++j) z = fmaf(xv[j], W2[j * 512 + col], z);
      float ls = fminf(z, 0.f) - log1pf(expf(-fabsf(z)));
      float g = fmaxf(ls * (1.f / 16.f), -3.f);
#pragma unroll
      for (int d = 1; d < 64; d <<= 1) {
        float up = __shfl_up(g, d, 64);
        if (lane >= d) g += up;
      }
      EQ[cl * 65 + lane] = expf(g);
      EK[cl * 65 + lane] = expf(fminf(-g, 80.f));
      if (vh == 0 && lane == 63)
        ebtot[((size_t)b * 16 + c) * 512 + col] = expf(g);
    }
  }
  __syncthreads();

  // ---- staging with gating applied (bit-identical to old global RMW path)
#pragma unroll
  for (int u2 = 0; u2 < 4; ++u2) {
    const int id = t + (u2 << 8);
    const int row = id >> 4, kg = id & 15;
    vu4 rq = *(const vu4*)(q16 + (rowbase + row) * 512 + h * 128 + kg * 8);
    vu4 rk = *(const vu4*)(k16 + (rowbase + row) * 512 + h * 128 + kg * 8);
    float qf[8], kf[8];
    unpack8(rq, qf); unpack8(rk, kf);
#pragma unroll
    for (int u = 0; u < 8; ++u) {
      qf[u] *= EQ[(kg * 8 + u) * 65 + row];
      kf[u] *= EK[(kg * 8 + u) * 65 + row];
    }
    vu4 pq = pack8(qf), pk4 = pack8(kf);
    *(vu4*)&Qs[row * 136 + kg * 8] = pq;
    *(vu4*)&Ks[row * 136 + kg * 8] = pk4;
    const unsigned short* kp = (const unsigned short*)&pk4;
#pragma unroll
    for (int u = 0; u < 8; ++u)
      Kt[(kg * 8 + u) * 68 + row] = kp[u];
    vu4 rv = *(const vu4*)(v + (rowbase + row) * 1024 + h * 256 + vh * 128 + kg * 8);
    const unsigned short* vp = (const unsigned short*)&rv;
#pragma unroll
    for (int u = 0; u < 8; ++u)
      Vt[(kg * 8 + u) * 68 + row] = vp[u];
  }
  __syncthreads();

  // phase 1: A = tril(Q K^T)
  {
    short8 af[4];
#pragma unroll
    for (int kf = 0; kf < 4; ++kf)
      af[kf] = *(const short8*)&Qs[(w * 16 + m) * 136 + kf * 32 + qd * 8];
    vf4 acc[4];
#pragma unroll
    for (int jt = 0; jt < 4; ++jt) acc[jt] = vzero();
#pragma unroll
    for (int jt = 0; jt < 4; ++jt)
#pragma unroll
      for (int kf = 0; kf < 4; ++kf) {
        short8 bfr = *(const short8*)&Ks[(jt * 16 + m) * 136 + kf * 32 + qd * 8];
        acc[jt] = __builtin_amdgcn_mfma_f32_16x16x32_bf16(af[kf], bfr, acc[jt], 0, 0, 0);
      }
#pragma unroll
    for (int jt = 0; jt < 4; ++jt)
#pragma unroll
      for (int r = 0; r < 4; ++r) {
        const int i = w * 16 + qd * 4 + r;
        const int j = jt * 16 + m;
        Asb[i * 68 + j] = f2bf((j <= i) ? acc[jt][r] : 0.f);
      }
  }
  __syncthreads();

  // phase 2: o_intra = A @ V
  {
    vf4 acc2[4][2];
#pragma unroll
    for (int mt = 0; mt < 4; ++mt) { acc2[mt][0] = vzero(); acc2[mt][1] = vzero(); }
#pragma unroll
    for (int kf = 0; kf < 2; ++kf) {
      short8 bf0 = *(const short8*)&Vt[(w * 32 + m) * 68 + kf * 32 + qd * 8];
      short8 bf1 = *(const short8*)&Vt[(w * 32 + 16 + m) * 68 + kf * 32 + qd * 8];
#pragma unroll
      for (int mt = 0; mt < 4; ++mt) {
        short8 af = *(const short8*)&Asb[(mt * 16 + m) * 68 + kf * 32 + qd * 8];
        acc2[mt][0] = __builtin_amdgcn_mfma_f32_16x16x32_bf16(af, bf0, acc2[mt][0], 0, 0, 0);
        acc2[mt][1] = __builtin_amdgcn_mfma_f32_16x16x32_bf16(af, bf1, acc2[mt][1], 0, 0, 0);
      }
    }
#pragma unroll
    for (int mt = 0; mt < 4; ++mt)
#pragma unroll
      for (int nt = 0; nt < 2; ++nt)
#pragma unroll
        for (int r = 0; r < 4; ++r) {
          const int i = mt * 16 + qd * 4 + r;
          const int vc = h * 256 + vh * 128 + w * 32 + nt * 16 + m;
          o[(rowbase + i) * 1024 + vc] = acc2[mt][nt][r];
        }
  }

  // phase 3: ST[v][k] = V^T @ K
  {
    short8 af3[2][2];
#pragma unroll
    for (int mt = 0; mt < 2; ++mt)
#pragma unroll
      for (int kf = 0; kf < 2; ++kf)
        af3[mt][kf] = *(const short8*)&Vt[(w * 32 + mt * 16 + m) * 68 + kf * 32 + qd * 8];
#pragma unroll
    for (int nt = 0; nt < 8; ++nt) {
      vf4 a0 = vzero(), a1 = vzero();
#pragma unroll
      for (int kf = 0; kf < 2; ++kf) {
        short8 bfr = *(const short8*)&Kt[(nt * 16 + m) * 68 + kf * 32 + qd * 8];
        a0 = __builtin_amdgcn_mfma_f32_16x16x32_bf16(af3[0][kf], bfr, a0, 0, 0, 0);
        a1 = __builtin_amdgcn_mfma_f32_16x16x32_bf16(af3[1][kf], bfr, a1, 0, 0, 0);
      }
      const size_t sbase = (size_t)(bh * 16 + c) * 256 + vh * 128 + w * 32;
#pragma unroll
      for (int r = 0; r < 4; ++r) {
        ST[(sbase + qd * 4 + r) * 128 + nt * 16 + m] = f2bf(a0[r]);
        ST[(sbase + 16 + qd * 4 + r) * 128 + nt * 16 + m] = f2bf(a1[r]);
      }
    }
  }
}

// ---------------------------------------------------------------------------
// State scan in place on bf16 ST[v][k]; fp32 carry; per-k decay vector.
// ---------------------------------------------------------------------------
__global__ __launch_bounds__(256)
void state_scan_k(unsigned short* __restrict__ ST, const float* __restrict__ ebtot) {
  const int idx = blockIdx.x * 256 + threadIdx.x;  // 0..32767
  const int kg = idx & 15;
  const int vv = (idx >> 4) & 255;
  const int bh = idx >> 12;
  const int b = bh >> 2, h = bh & 3;
  float s[8];
#pragma unroll
  for (int u = 0; u < 8; ++u) s[u] = 0.f;
  for (int c = 0; c < 16; ++c) {
    unsigned short* p = ST + ((size_t)(bh * 16 + c) * 256 + vv) * 128 + kg * 8;
    const float* ep = ebtot + ((size_t)b * 16 + c) * 512 + h * 128 + kg * 8;
    float e[8];
    *(vf4*)&e[0] = *(const vf4*)ep;
    *(vf4*)&e[4] = *(const vf4*)(ep + 4);
    float kv[8];
    unpack8(*(const vu4*)p, kv);
    *(vu4*)p = pack8(s);
#pragma unroll
    for (int u = 0; u < 8; ++u) s[u] = (s[u] + kv[u]) * e[u];
  }
}

// ---------------------------------------------------------------------------
// o += Q~ @ S_c with in-block q-gating. grid (vt2, chunk16, bh8) = 256 blocks.
// LDS: 17408 + 34816 + 33280 = 85504 B.
// ---------------------------------------------------------------------------
__global__ __launch_bounds__(256)
void o_inter_gate_k(const float* __restrict__ xl, const float* __restrict__ W2,
                    const float* __restrict__ bias,
                    const unsigned short* __restrict__ q16,
                    const unsigned short* __restrict__ ST, float* __restrict__ o) {
  __shared__ __align__(16) unsigned short Qs[64 * 136];
  __shared__ __align__(16) unsigned short Ss[128 * 136];
  __shared__ float EQ[128 * 65];
  const int t = threadIdx.x;
  const int vt = blockIdx.x, c = blockIdx.y, bh = blockIdx.z;
  const int b = bh >> 2, h = bh & 3;
  const size_t rowbase = (size_t)b * 1024 + c * 64;
  const int w = t >> 6, lane = t & 63;
  const int qd = lane >> 4, m = lane & 15;

  // ---- gate phase (q factors only; identical op order)
  {
    const float* xp = xl + (rowbase + lane) * 16;
    float xv[16];
#pragma unroll
    for (int u = 0; u < 4; ++u)
      *(vf4*)&xv[u * 4] = *(const vf4*)(xp + u * 4);
#pragma unroll
    for (int cc = 0; cc < 32; ++cc) {
      const int cl = w * 32 + cc;
      const int col = h * 128 + cl;
      float z = bias[col];
#pragma unroll
      for (int j = 0; j < 16; ++j) z = fmaf(xv[j], W2[j * 512 + col], z);
      float ls = fminf(z, 0.f) - log1pf(expf(-fabsf(z)));
      float g = fmaxf(ls * (1.f / 16.f), -3.f);
#pragma unroll
      for (int d = 1; d < 64; d <<= 1) {
        float up = __shfl_up(g, d, 64);
        if (lane >= d) g += up;
      }
      EQ[cl * 65 + lane] = expf(g);
    }
  }
  __syncthreads();

#pragma unroll
  for (int u2 = 0; u2 < 4; ++u2) {
    const int id = t + (u2 << 8);
    const int row = id >> 4, kg = id & 15;
    vu4 rq = *(const vu4*)(q16 + (rowbase + row) * 512 + h * 128 + kg * 8);
    float qf[8];
    unpack8(rq, qf);
#pragma unroll
    for (int u = 0; u < 8; ++u) qf[u] *= EQ[(kg * 8 + u) * 65 + row];
    *(vu4*)&Qs[row * 136 + kg * 8] = pack8(qf);
  }
#pragma unroll
  for (int u2 = 0; u2 < 8; ++u2) {
    const int id = t + (u2 << 8);
    const int vrow = id >> 4, kg = id & 15;
    *(vu4*)&Ss[vrow * 136 + kg * 8] =
        *(const vu4*)(ST + ((size_t)(bh * 16 + c) * 256 + vt * 128 + vrow) * 128 + kg * 8);
  }
  __syncthreads();

  short8 af[4];
#pragma unroll
  for (int kf = 0; kf < 4; ++kf)
    af[kf] = *(const short8*)&Qs[(w * 16 + m) * 136 + kf * 32 + qd * 8];
#pragma unroll
  for (int nt = 0; nt < 8; ++nt) {
    vf4 acc = vzero();
#pragma unroll
    for (int kf = 0; kf < 4; ++kf) {
      short8 bfr = *(const short8*)&Ss[(nt * 16 + m) * 136 + kf * 32 + qd * 8];
      acc = __builtin_amdgcn_mfma_f32_16x16x32_bf16(af[kf], bfr, acc, 0, 0, 0);
    }
    float* base = o + (rowbase + w * 16 + qd * 4) * 1024 + h * 256 + vt * 128 + nt * 16 + m;
#pragma unroll
    for (int r = 0; r < 4; ++r)
      base[(size_t)r * 1024] += acc[r];
  }
}

// ---------------------------------------------------------------------------
// RMSNorm over DV=256 + silu-gate (vectorized, wave-per-group). grid 2048.
// ---------------------------------------------------------------------------
__global__ __launch_bounds__(256)
void norm_gate_k(const float* __restrict__ o, const float* __restrict__ rmsw,
                 const unsigned short* __restrict__ sg,
                 unsigned short* __restrict__ ob) {
  const int t = threadIdx.x;
  const int w = t >> 6, lane = t & 63;
  const int grp = blockIdx.x * 4 + w;   // 0..8191
  const int row = grp >> 2, h = grp & 3;
  const size_t base = (size_t)row * 1024 + h * 256 + lane * 4;
  vf4 val = *(const vf4*)(o + base);
  float ss = val.x * val.x + val.y * val.y + val.z * val.z + val.w * val.w;
#pragma unroll
  for (int mm = 1; mm < 64; mm <<= 1) ss += __shfl_xor(ss, mm, 64);
  const float scale = rsqrtf(ss * (1.f / 256.f) + 1e-5f);
  us4 sgv = *(const us4*)(sg + base);
  vf4 rw = *(const vf4*)(rmsw + lane * 4);
  us4 outv;
  outv.x = f2bf(val.x * scale * rw.x * bf2f((unsigned int)sgv.x));
  outv.y = f2bf(val.y * scale * rw.y * bf2f((unsigned int)sgv.y));
  outv.z = f2bf(val.z * scale * rw.z * bf2f((unsigned int)sgv.z));
  outv.w = f2bf(val.w * scale * rw.w * bf2f((unsigned int)sgv.w));
  *(us4*)(ob + base) = outv;
}

// ---------------------------------------------------------------------------
// MFMA output GEMM (round-13, unchanged). grid (8,32) = 256 blocks.
// ---------------------------------------------------------------------------
__global__ __launch_bounds__(256)
void out_mfma_k(const unsigned short* __restrict__ Ab,
                const unsigned short* __restrict__ woT, float* __restrict__ Y) {
  __shared__ __align__(16) unsigned short As[64 * 64];
  __shared__ __align__(16) unsigned short Bs[128 * 64];
  const int t = threadIdx.x;
  const int m0 = blockIdx.y << 6;
  const int n0 = blockIdx.x << 7;
  const int w = t >> 6, lane = t & 63;
  const int wm = (w >> 1) * 32, wn = (w & 1) * 64;
  const int qd = lane >> 4, m = lane & 15;
  const int srow = lane >> 3;
  const int scol = ((lane & 7) ^ srow) << 3;

  vf4 acc[2][4];
#pragma unroll
  for (int i = 0; i < 2; ++i)
#pragma unroll
    for (int j = 0; j < 4; ++j) acc[i][j] = vzero();

  for (int k0 = 0; k0 < 1024; k0 += 64) {
    __syncthreads();
#pragma unroll
    for (int cc = 0; cc < 2; ++cc) {
      const int c = (w << 1) + cc;
      const int row = (c << 3) + srow;
      gld16(Ab + (size_t)(m0 + row) * 1024 + k0 + scol, (unsigned short*)As + (c << 9));
    }
#pragma unroll
    for (int cc = 0; cc < 4; ++cc) {
      const int c = (w << 2) + cc;
      const int row = (c << 3) + srow;
      gld16(woT + (size_t)(n0 + row) * 1024 + k0 + scol, (unsigned short*)Bs + (c << 9));
    }
    __syncthreads();
#pragma unroll
    for (int ks = 0; ks < 2; ++ks) {
      const int sw = (((ks << 2) + qd) ^ (m & 7)) << 3;
      short8 af[2], bf[4];
#pragma unroll
      for (int i = 0; i < 2; ++i)
        af[i] = *(const short8*)&As[(wm + i * 16 + m) * 64 + sw];
#pragma unroll
      for (int j = 0; j < 4; ++j)
        bf[j] = *(const short8*)&Bs[(wn + j * 16 + m) * 64 + sw];
#pragma unroll
      for (int i = 0; i < 2; ++i)
#pragma unroll
        for (int j = 0; j < 4; ++j)
          acc[i][j] = __builtin_amdgcn_mfma_f32_16x16x32_bf16(af[i], bf[j], acc[i][j], 0, 0, 0);
    }
  }
#pragma unroll
  for (int i = 0; i < 2; ++i)
#pragma unroll
    for (int j = 0; j < 4; ++j)
#pragma unroll
      for (int r = 0; r < 4; ++r) {
        const int grow = m0 + wm + i * 16 + qd * 4 + r;
        const int gcol = n0 + wn + j * 16 + m;
        Y[(size_t)grow * 1024 + gcol] = acc[i][j][r];
      }
}

// ---------------------------------------------------------------------------
extern "C" void kernel_launch(void* const* d_in, const int* in_sizes, int n_in,
                              void* d_out, int out_size, void* d_ws, size_t ws_size,
                              hipStream_t stream) {
  const float* x    = (const float*)d_in[0];
  const float* Wq   = (const float*)d_in[1];
  const float* Wk   = (const float*)d_in[2];
  const float* Wv   = (const float*)d_in[3];
  const float* Wg   = (const float*)d_in[4];
  const float* Wgk1 = (const float*)d_in[5];
  const float* Wgk2 = (const float*)d_in[6];
  const float* bgk2 = (const float*)d_in[7];
  const float* Wout = (const float*)d_in[8];
  const float* rmsw = (const float*)d_in[9];

  const size_t MB = 1u << 20;
  char* w = (char*)d_ws;
  unsigned short* qb16   = (unsigned short*)(w);           // [0,2) MB bf16 (RAW q)
  unsigned short* kb16   = (unsigned short*)(w + 2 * MB);  // [2,4)       (RAW k)
  unsigned short* vbuf   = (unsigned short*)(w + 4 * MB);  // [4,8)
  unsigned short* sgbuf  = (unsigned short*)(w + 8 * MB);  // [8,12)
  float*          obuf   = (float*)(w + 12 * MB);          // [12,20) fp32
  char*           sreg   = w + 20 * MB;                    // [20,28) multi-phase
  unsigned short* xb     = (unsigned short*)sreg;          //   phase 0: 4 MB
  unsigned short* STbuf  = (unsigned short*)sreg;          //   phase A: 8 MB [v][k]
  unsigned short* obuf_b = (unsigned short*)sreg;          //   phase B: 4 MB
  float*          xlbuf  = (float*)(w + 28 * MB);          // 128 KB
  float*          ebbuf  = (float*)(w + 28 * MB + 131072); // 64 KB
  unsigned short* wqT    = (unsigned short*)(w + 29 * MB); // 1 MB
  unsigned short* wkT    = (unsigned short*)(w + 30 * MB); // 1 MB
  unsigned short* wvT    = (unsigned short*)(w + 31 * MB); // 2 MB
  unsigned short* wgT    = (unsigned short*)(w + 33 * MB); // 2 MB
  unsigned short* woT    = (unsigned short*)(w + 35 * MB); // 2 MB

  prep_lowrank_k<<<2048, 256, 0, stream>>>(Wq, Wk, Wv, Wg, Wout, x, Wgk1,
                                           wqT, wkT, wvT, wgT, woT, xb, xlbuf);
  proj_mfma_k<<<dim3(24, 16), 256, 0, stream>>>(xb, wqT, wkT, wvT, wgT, qb16, kb16, vbuf, sgbuf);
  intra_gate_k<<<dim3(2, 16, 8), 256, 0, stream>>>(xlbuf, Wgk2, bgk2, qb16, kb16, vbuf,
                                                   obuf, STbuf, ebbuf);
  state_scan_k<<<128, 256, 0, stream>>>(STbuf, ebbuf);
  o_inter_gate_k<<<dim3(2, 16, 8), 256, 0, stream>>>(xlbuf, Wgk2, bgk2, qb16, STbuf, obuf);
  norm_gate_k<<<2048, 256, 0, stream>>>(obuf, rmsw, sgbuf, obuf_b);
  out_mfma_k<<<dim3(8, 32), 256, 0, stream>>>(obuf_b, woT, (float*)d_out);
}

// Round 4
// 194.407 us; speedup vs baseline: 1.6738x; 1.1857x over previous
//
#include <hip/hip_runtime.h>
#include <math.h>

// GLA: B=2, N=1024, D=1024, H=4, KD=512, VD=1024, DK=128, DV=256, LR=16
// Round 16: revert round-15's LDS-occupancy regression (separate gate_scan,
// round-0 intra_kv/o_inter), and split/rebuild prep:
//   wtrans_k  : W transpose+cvt, 2 tiles/block, all loads up-front, double
//               LDS buffer, ONE sync (load latency hidden under LDS phase).
//   xcvt_lr_k : x fp32->bf16 pure streaming (no LDS) + lowrank xl=x@Wgk1.
// GEMMs keep gld16+XOR swizzle (round-13). norm_gate vectorized (validated).
// 9 kernels. All math element-identical to the 194us baseline.

typedef __attribute__((ext_vector_type(4))) float vf4;
typedef __attribute__((ext_vector_type(4))) unsigned int vu4;
typedef __attribute__((ext_vector_type(8))) short short8;
typedef __attribute__((ext_vector_type(4))) unsigned short us4;

#define DEVI static __device__ __forceinline__
DEVI vf4 vzero() { vf4 x = {0.f, 0.f, 0.f, 0.f}; return x; }

DEVI float bf2f(unsigned int u) {
  union { unsigned int i; float f; } c; c.i = u << 16; return c.f;
}
DEVI unsigned short f2bf(float f) {
  union { float f; unsigned int i; } c; c.f = f;
  unsigned int i = c.i;
  return (unsigned short)((i + 0x7fffu + ((i >> 16) & 1u)) >> 16);
}
DEVI void unpack8(vu4 r, float* f) {
  f[0] = bf2f(r.x & 0xffffu); f[1] = bf2f(r.x >> 16);
  f[2] = bf2f(r.y & 0xffffu); f[3] = bf2f(r.y >> 16);
  f[4] = bf2f(r.z & 0xffffu); f[5] = bf2f(r.z >> 16);
  f[6] = bf2f(r.w & 0xffffu); f[7] = bf2f(r.w >> 16);
}
DEVI vu4 pack8(const float* f) {
  vu4 o;
  o.x = (unsigned int)f2bf(f[0]) | ((unsigned int)f2bf(f[1]) << 16);
  o.y = (unsigned int)f2bf(f[2]) | ((unsigned int)f2bf(f[3]) << 16);
  o.z = (unsigned int)f2bf(f[4]) | ((unsigned int)f2bf(f[5]) << 16);
  o.w = (unsigned int)f2bf(f[6]) | ((unsigned int)f2bf(f[7]) << 16);
  return o;
}

DEVI void gld16(const unsigned short* g, unsigned short* l) {
  __builtin_amdgcn_global_load_lds(
      (const __attribute__((address_space(1))) unsigned int*)g,
      (__attribute__((address_space(3))) unsigned int*)l,
      16, 0, 0);
}

// ---------------------------------------------------------------------------
// wtrans_k: weight transpose + fp32->bf16. 2 tiles (64x64) per block,
// loads all issued before the single sync. grid 512 x 256.
// ---------------------------------------------------------------------------
__global__ __launch_bounds__(256)
void wtrans_k(const float* __restrict__ Wq, const float* __restrict__ Wk,
              const float* __restrict__ Wv, const float* __restrict__ Wg,
              const float* __restrict__ Wo,
              unsigned short* __restrict__ wqT, unsigned short* __restrict__ wkT,
              unsigned short* __restrict__ wvT, unsigned short* __restrict__ wgT,
              unsigned short* __restrict__ woT) {
  __shared__ float T[2][64][65];
  const int t = threadIdx.x;
  const int r = t >> 2, s = t & 3;
  float f[2][16];
  const float* srcs[2];
  unsigned short* dsts[2];
#pragma unroll
  for (int i = 0; i < 2; ++i) {
    const int tid = blockIdx.x * 2 + i;   // 0..1023
    const float* W; unsigned short* O; int kt, cb, N;
    if (tid < 128)       { W = Wq; O = wqT; N = 512;  kt = tid >> 3;          cb = tid & 7;  }
    else if (tid < 256)  { W = Wk; O = wkT; N = 512;  kt = (tid - 128) >> 3;  cb = tid & 7;  }
    else if (tid < 512)  { W = Wv; O = wvT; N = 1024; kt = (tid - 256) >> 4;  cb = tid & 15; }
    else if (tid < 768)  { W = Wg; O = wgT; N = 1024; kt = (tid - 512) >> 4;  cb = tid & 15; }
    else                 { W = Wo; O = woT; N = 1024; kt = (tid - 768) >> 4;  cb = tid & 15; }
    srcs[i] = W + (size_t)(kt * 64 + r) * N + cb * 64 + s * 16;
    dsts[i] = O + (size_t)(cb * 64 + r) * 1024 + kt * 64 + s * 16;
  }
  // issue all 8 vector loads up-front (both tiles)
#pragma unroll
  for (int i = 0; i < 2; ++i)
#pragma unroll
    for (int u = 0; u < 4; ++u)
      *(vf4*)&f[i][u * 4] = *(const vf4*)(srcs[i] + u * 4);
  // LDS writes (bank: (r + col) & 31, 2-way = free)
#pragma unroll
  for (int i = 0; i < 2; ++i)
#pragma unroll
    for (int u = 0; u < 16; ++u)
      T[i][r][s * 16 + u] = f[i][u];
  __syncthreads();
  // transposed read (role swap: r = n-local, s = k-group), cvt, store
#pragma unroll
  for (int i = 0; i < 2; ++i) {
    unsigned int pk[8];
#pragma unroll
    for (int u = 0; u < 8; ++u) {
      unsigned int lo = f2bf(T[i][s * 16 + 2 * u][r]);
      unsigned int hi = f2bf(T[i][s * 16 + 2 * u + 1][r]);
      pk[u] = lo | (hi << 16);
    }
    *(vu4*)dsts[i] = *(vu4*)&pk[0];
    *(vu4*)(dsts[i] + 8) = *(vu4*)&pk[4];
  }
}

// ---------------------------------------------------------------------------
// xcvt_lr_k: bid<512 -> x fp32->bf16 flat streaming; bid>=512 -> lowrank.
// grid 1024 x 256.
// ---------------------------------------------------------------------------
__global__ __launch_bounds__(256)
void xcvt_lr_k(const float* __restrict__ X, const float* __restrict__ Wgk1,
               unsigned short* __restrict__ xb, float* __restrict__ xl) {
  const int bid = blockIdx.x, t = threadIdx.x;
  if (bid < 512) {  // ---- x convert: 512*256*16 = 2M elements, 64B/lane
    const size_t base = (size_t)bid * 4096 + t * 16;
    float f[16];
    *(vf4*)&f[0]  = *(const vf4*)(X + base);
    *(vf4*)&f[4]  = *(const vf4*)(X + base + 4);
    *(vf4*)&f[8]  = *(const vf4*)(X + base + 8);
    *(vf4*)&f[12] = *(const vf4*)(X + base + 12);
    *(vu4*)(xb + base) = pack8(f);
    *(vu4*)(xb + base + 8) = pack8(f + 8);
    return;
  }
  // ---- lowrank: xl = x @ Wgk1, one wave per row
  const int w = t >> 6, lane = t & 63;
  const int row = (bid - 512) * 4 + w;
  float acc[16];
#pragma unroll
  for (int c2 = 0; c2 < 16; ++c2) acc[c2] = 0.f;
  const float* xp = X + (size_t)row * 1024 + lane * 16;
  float xv[16];
#pragma unroll
  for (int u = 0; u < 4; ++u)
    *(vf4*)&xv[u * 4] = *(const vf4*)(xp + u * 4);
#pragma unroll
  for (int j = 0; j < 16; ++j) {
    const float* wp = Wgk1 + (size_t)(lane * 16 + j) * 16;
    float wv[16];
#pragma unroll
    for (int u = 0; u < 4; ++u)
      *(vf4*)&wv[u * 4] = *(const vf4*)(wp + u * 4);
#pragma unroll
    for (int c2 = 0; c2 < 16; ++c2) acc[c2] = fmaf(xv[j], wv[c2], acc[c2]);
  }
#pragma unroll
  for (int mm = 1; mm < 64; mm <<= 1) {
#pragma unroll
    for (int c2 = 0; c2 < 16; ++c2) acc[c2] += __shfl_xor(acc[c2], mm, 64);
  }
  if (lane == 0) {
#pragma unroll
    for (int c2 = 0; c2 < 16; ++c2) xl[(size_t)row * 16 + c2] = acc[c2];
  }
}

// ---------------------------------------------------------------------------
// MFMA projection (round-13, unchanged). grid (24,16) = 384 blocks.
// ---------------------------------------------------------------------------
__global__ __launch_bounds__(256)
void proj_mfma_k(const unsigned short* __restrict__ xb,
                 const unsigned short* __restrict__ wqT, const unsigned short* __restrict__ wkT,
                 const unsigned short* __restrict__ wvT, const unsigned short* __restrict__ wgT,
                 unsigned short* __restrict__ qb, unsigned short* __restrict__ kb,
                 unsigned short* __restrict__ vb, unsigned short* __restrict__ sgb) {
  __shared__ __align__(16) unsigned short As[128 * 64];
  __shared__ __align__(16) unsigned short Bs[128 * 64];
  const int t = threadIdx.x;
  const int m0 = blockIdx.y << 7;
  const int nt = blockIdx.x;
  const unsigned short* WT; int n0; int kind;
  if (nt < 4)       { WT = wqT; n0 = nt << 7;        kind = 0; }
  else if (nt < 8)  { WT = wkT; n0 = (nt - 4) << 7;  kind = 1; }
  else if (nt < 16) { WT = wvT; n0 = (nt - 8) << 7;  kind = 2; }
  else              { WT = wgT; n0 = (nt - 16) << 7; kind = 3; }

  const int w = t >> 6, lane = t & 63;
  const int wm = (w >> 1) << 6, wn = (w & 1) << 6;
  const int qd = lane >> 4, m = lane & 15;
  const int srow = lane >> 3;
  const int scol = ((lane & 7) ^ srow) << 3;

  vf4 acc[4][4];
#pragma unroll
  for (int i = 0; i < 4; ++i)
#pragma unroll
    for (int j = 0; j < 4; ++j) acc[i][j] = vzero();

  for (int k0 = 0; k0 < 1024; k0 += 64) {
    __syncthreads();
#pragma unroll
    for (int cc = 0; cc < 4; ++cc) {
      const int c = (w << 2) + cc;
      const int row = (c << 3) + srow;
      gld16(xb + (size_t)(m0 + row) * 1024 + k0 + scol, (unsigned short*)As + (c << 9));
      gld16(WT + (size_t)(n0 + row) * 1024 + k0 + scol, (unsigned short*)Bs + (c << 9));
    }
    __syncthreads();
#pragma unroll
    for (int ks = 0; ks < 2; ++ks) {
      const int sw = (((ks << 2) + qd) ^ (m & 7)) << 3;
      short8 af[4], bf[4];
#pragma unroll
      for (int i = 0; i < 4; ++i)
        af[i] = *(const short8*)&As[(wm + i * 16 + m) * 64 + sw];
#pragma unroll
      for (int j = 0; j < 4; ++j)
        bf[j] = *(const short8*)&Bs[(wn + j * 16 + m) * 64 + sw];
#pragma unroll
      for (int i = 0; i < 4; ++i)
#pragma unroll
        for (int j = 0; j < 4; ++j)
          acc[i][j] = __builtin_amdgcn_mfma_f32_16x16x32_bf16(af[i], bf[j], acc[i][j], 0, 0, 0);
    }
  }
#pragma unroll
  for (int i = 0; i < 4; ++i) {
#pragma unroll
    for (int j = 0; j < 4; ++j) {
#pragma unroll
      for (int r = 0; r < 4; ++r) {
        const int grow = m0 + wm + i * 16 + qd * 4 + r;
        const int gcol = n0 + wn + j * 16 + m;
        float val = acc[i][j][r];
        if (kind == 0)      qb[(size_t)grow * 512 + gcol] = f2bf(val);
        else if (kind == 1) kb[(size_t)grow * 512 + gcol] = f2bf(val);
        else if (kind == 2) vb[(size_t)grow * 1024 + gcol] = f2bf(val);
        else {
          val = val / (1.f + expf(-val));
          sgb[(size_t)grow * 1024 + gcol] = f2bf(val);
        }
      }
    }
  }
}

// ---------------------------------------------------------------------------
// gate_scan (round-0): one wave per (b, chunk, 16-kcol group). grid 256 x 256.
// ---------------------------------------------------------------------------
__global__ __launch_bounds__(256)
void gate_scan_k(const float* __restrict__ xl, const float* __restrict__ W2,
                 const float* __restrict__ bias,
                 unsigned short* __restrict__ q, unsigned short* __restrict__ k,
                 float* __restrict__ ebtot) {
  const int t = threadIdx.x;
  const int w = t >> 6, lane = t & 63;
  const int wid = blockIdx.x * 4 + w;     // 0..1023
  const int kt = wid & 31;                // 16-col group
  const int c = (wid >> 5) & 15;
  const int b = wid >> 9;
  const int kbase = kt * 16;
  const size_t rowbase = (size_t)b * 1024 + c * 64;

  const float* xp = xl + (rowbase + lane) * 16;
  float xv[16];
#pragma unroll
  for (int u = 0; u < 4; ++u)
    *(vf4*)&xv[u * 4] = *(const vf4*)(xp + u * 4);

  const size_t a = (rowbase + lane) * 512 + kbase;
  vu4 qr0 = *(const vu4*)(q + a), qr1 = *(const vu4*)(q + a + 8);
  vu4 kr0 = *(const vu4*)(k + a), kr1 = *(const vu4*)(k + a + 8);
  float qf[16], kf[16];
  unpack8(qr0, qf); unpack8(qr1, qf + 8);
  unpack8(kr0, kf); unpack8(kr1, kf + 8);

  float gf[16];
#pragma unroll
  for (int cc = 0; cc < 16; ++cc) {
    const int col = kbase + cc;           // wave-uniform
    float z = bias[col];
#pragma unroll
    for (int j = 0; j < 16; ++j) z = fmaf(xv[j], W2[j * 512 + col], z);
    float ls = fminf(z, 0.f) - log1pf(expf(-fabsf(z)));
    float g = fmaxf(ls * (1.f / 16.f), -3.f);
#pragma unroll
    for (int d = 1; d < 64; d <<= 1) {
      float up = __shfl_up(g, d, 64);
      if (lane >= d) g += up;
    }
    qf[cc] *= expf(g);
    kf[cc] *= expf(fminf(-g, 80.f));
    gf[cc] = g;
  }
  *(vu4*)(q + a) = pack8(qf);
  *(vu4*)(q + a + 8) = pack8(qf + 8);
  *(vu4*)(k + a) = pack8(kf);
  *(vu4*)(k + a + 8) = pack8(kf + 8);
  if (lane == 63) {
    float* ep = ebtot + ((size_t)b * 16 + c) * 512 + kbase;
#pragma unroll
    for (int cc = 0; cc < 16; ++cc) ep[cc] = expf(gf[cc]);
  }
}

// ---------------------------------------------------------------------------
// Fused intra+kv (round-0). grid (vh2, chunk16, bh8) = 256 blocks.
// ---------------------------------------------------------------------------
__global__ __launch_bounds__(256)
void intra_kv_k(const unsigned short* __restrict__ q16, const unsigned short* __restrict__ k16,
                const unsigned short* __restrict__ v, float* __restrict__ o,
                unsigned short* __restrict__ ST) {
  __shared__ __align__(16) unsigned short Qs[64 * 136];
  __shared__ __align__(16) unsigned short Ks[64 * 136];
  __shared__ __align__(16) unsigned short Kt[128 * 68];
  __shared__ __align__(16) unsigned short Vt[128 * 68];
  __shared__ __align__(16) unsigned short Asb[64 * 68];
  const int t = threadIdx.x;
  const int vh = blockIdx.x, c = blockIdx.y, bh = blockIdx.z;
  const int b = bh >> 2, h = bh & 3;
  const size_t rowbase = (size_t)b * 1024 + c * 64;

#pragma unroll
  for (int u2 = 0; u2 < 4; ++u2) {
    const int id = t + (u2 << 8);
    const int row = id >> 4, kg = id & 15;
    vu4 rq = *(const vu4*)(q16 + (rowbase + row) * 512 + h * 128 + kg * 8);
    *(vu4*)&Qs[row * 136 + kg * 8] = rq;
    vu4 rk = *(const vu4*)(k16 + (rowbase + row) * 512 + h * 128 + kg * 8);
    *(vu4*)&Ks[row * 136 + kg * 8] = rk;
    const unsigned short* kp = (const unsigned short*)&rk;
#pragma unroll
    for (int u = 0; u < 8; ++u)
      Kt[(kg * 8 + u) * 68 + row] = kp[u];
    vu4 rv = *(const vu4*)(v + (rowbase + row) * 1024 + h * 256 + vh * 128 + kg * 8);
    const unsigned short* vp = (const unsigned short*)&rv;
#pragma unroll
    for (int u = 0; u < 8; ++u)
      Vt[(kg * 8 + u) * 68 + row] = vp[u];
  }
  __syncthreads();

  const int w = t >> 6, lane = t & 63;
  const int qd = lane >> 4, m = lane & 15;

  // phase 1: A = tril(Q K^T)
  {
    short8 af[4];
#pragma unroll
    for (int kf = 0; kf < 4; ++kf)
      af[kf] = *(const short8*)&Qs[(w * 16 + m) * 136 + kf * 32 + qd * 8];
    vf4 acc[4];
#pragma unroll
    for (int jt = 0; jt < 4; ++jt) acc[jt] = vzero();
#pragma unroll
    for (int jt = 0; jt < 4; ++jt)
#pragma unroll
      for (int kf = 0; kf < 4; ++kf) {
        short8 bfr = *(const short8*)&Ks[(jt * 16 + m) * 136 + kf * 32 + qd * 8];
        acc[jt] = __builtin_amdgcn_mfma_f32_16x16x32_bf16(af[kf], bfr, acc[jt], 0, 0, 0);
      }
#pragma unroll
    for (int jt = 0; jt < 4; ++jt)
#pragma unroll
      for (int r = 0; r < 4; ++r) {
        const int i = w * 16 + qd * 4 + r;
        const int j = jt * 16 + m;
        Asb[i * 68 + j] = f2bf((j <= i) ? acc[jt][r] : 0.f);
      }
  }
  __syncthreads();

  // phase 2: o_intra = A @ V
  {
    vf4 acc2[4][2];
#pragma unroll
    for (int mt = 0; mt < 4; ++mt) { acc2[mt][0] = vzero(); acc2[mt][1] = vzero(); }
#pragma unroll
    for (int kf = 0; kf < 2; ++kf) {
      short8 bf0 = *(const short8*)&Vt[(w * 32 + m) * 68 + kf * 32 + qd * 8];
      short8 bf1 = *(const short8*)&Vt[(w * 32 + 16 + m) * 68 + kf * 32 + qd * 8];
#pragma unroll
      for (int mt = 0; mt < 4; ++mt) {
        short8 af = *(const short8*)&Asb[(mt * 16 + m) * 68 + kf * 32 + qd * 8];
        acc2[mt][0] = __builtin_amdgcn_mfma_f32_16x16x32_bf16(af, bf0, acc2[mt][0], 0, 0, 0);
        acc2[mt][1] = __builtin_amdgcn_mfma_f32_16x16x32_bf16(af, bf1, acc2[mt][1], 0, 0, 0);
      }
    }
#pragma unroll
    for (int mt = 0; mt < 4; ++mt)
#pragma unroll
      for (int nt = 0; nt < 2; ++nt)
#pragma unroll
        for (int r = 0; r < 4; ++r) {
          const int i = mt * 16 + qd * 4 + r;
          const int vc = h * 256 + vh * 128 + w * 32 + nt * 16 + m;
          o[(rowbase + i) * 1024 + vc] = acc2[mt][nt][r];
        }
  }

  // phase 3: ST[v][k] = V^T @ K
  {
    short8 af3[2][2];
#pragma unroll
    for (int mt = 0; mt < 2; ++mt)
#pragma unroll
      for (int kf = 0; kf < 2; ++kf)
        af3[mt][kf] = *(const short8*)&Vt[(w * 32 + mt * 16 + m) * 68 + kf * 32 + qd * 8];
#pragma unroll
    for (int nt = 0; nt < 8; ++nt) {
      vf4 a0 = vzero(), a1 = vzero();
#pragma unroll
      for (int kf = 0; kf < 2; ++kf) {
        short8 bfr = *(const short8*)&Kt[(nt * 16 + m) * 68 + kf * 32 + qd * 8];
        a0 = __builtin_amdgcn_mfma_f32_16x16x32_bf16(af3[0][kf], bfr, a0, 0, 0, 0);
        a1 = __builtin_amdgcn_mfma_f32_16x16x32_bf16(af3[1][kf], bfr, a1, 0, 0, 0);
      }
      const size_t sbase = (size_t)(bh * 16 + c) * 256 + vh * 128 + w * 32;
#pragma unroll
      for (int r = 0; r < 4; ++r) {
        ST[(sbase + qd * 4 + r) * 128 + nt * 16 + m] = f2bf(a0[r]);
        ST[(sbase + 16 + qd * 4 + r) * 128 + nt * 16 + m] = f2bf(a1[r]);
      }
    }
  }
}

// ---------------------------------------------------------------------------
// State scan in place on bf16 ST[v][k]; fp32 carry; per-k decay vector.
// ---------------------------------------------------------------------------
__global__ __launch_bounds__(256)
void state_scan_k(unsigned short* __restrict__ ST, const float* __restrict__ ebtot) {
  const int idx = blockIdx.x * 256 + threadIdx.x;  // 0..32767
  const int kg = idx & 15;
  const int vv = (idx >> 4) & 255;
  const int bh = idx >> 12;
  const int b = bh >> 2, h = bh & 3;
  float s[8];
#pragma unroll
  for (int u = 0; u < 8; ++u) s[u] = 0.f;
  for (int c = 0; c < 16; ++c) {
    unsigned short* p = ST + ((size_t)(bh * 16 + c) * 256 + vv) * 128 + kg * 8;
    const float* ep = ebtot + ((size_t)b * 16 + c) * 512 + h * 128 + kg * 8;
    float e[8];
    *(vf4*)&e[0] = *(const vf4*)ep;
    *(vf4*)&e[4] = *(const vf4*)(ep + 4);
    float kv[8];
    unpack8(*(const vu4*)p, kv);
    *(vu4*)p = pack8(s);
#pragma unroll
    for (int u = 0; u < 8; ++u) s[u] = (s[u] + kv[u]) * e[u];
  }
}

// ---------------------------------------------------------------------------
// o += Q~ @ S_c via MFMA (round-0). grid (vt2, chunk16, bh8) = 256 blocks.
// ---------------------------------------------------------------------------
__global__ __launch_bounds__(256)
void o_inter_k(const unsigned short* __restrict__ q16, const unsigned short* __restrict__ ST,
               float* __restrict__ o) {
  __shared__ __align__(16) unsigned short Qs[64 * 136];
  __shared__ __align__(16) unsigned short Ss[128 * 136];
  const int t = threadIdx.x;
  const int vt = blockIdx.x, c = blockIdx.y, bh = blockIdx.z;
  const int b = bh >> 2, h = bh & 3;
  const size_t rowbase = (size_t)b * 1024 + c * 64;

#pragma unroll
  for (int u2 = 0; u2 < 4; ++u2) {
    const int id = t + (u2 << 8);
    const int row = id >> 4, kg = id & 15;
    *(vu4*)&Qs[row * 136 + kg * 8] =
        *(const vu4*)(q16 + (rowbase + row) * 512 + h * 128 + kg * 8);
  }
#pragma unroll
  for (int u2 = 0; u2 < 8; ++u2) {
    const int id = t + (u2 << 8);
    const int vrow = id >> 4, kg = id & 15;
    *(vu4*)&Ss[vrow * 136 + kg * 8] =
        *(const vu4*)(ST + ((size_t)(bh * 16 + c) * 256 + vt * 128 + vrow) * 128 + kg * 8);
  }
  __syncthreads();

  const int w = t >> 6, lane = t & 63;
  const int qd = lane >> 4, m = lane & 15;
  short8 af[4];
#pragma unroll
  for (int kf = 0; kf < 4; ++kf)
    af[kf] = *(const short8*)&Qs[(w * 16 + m) * 136 + kf * 32 + qd * 8];
#pragma unroll
  for (int nt = 0; nt < 8; ++nt) {
    vf4 acc = vzero();
#pragma unroll
    for (int kf = 0; kf < 4; ++kf) {
      short8 bfr = *(const short8*)&Ss[(nt * 16 + m) * 136 + kf * 32 + qd * 8];
      acc = __builtin_amdgcn_mfma_f32_16x16x32_bf16(af[kf], bfr, acc, 0, 0, 0);
    }
    float* base = o + (rowbase + w * 16 + qd * 4) * 1024 + h * 256 + vt * 128 + nt * 16 + m;
#pragma unroll
    for (int r = 0; r < 4; ++r)
      base[(size_t)r * 1024] += acc[r];
  }
}

// ---------------------------------------------------------------------------
// RMSNorm over DV=256 + silu-gate (vectorized, wave-per-group). grid 2048.
// ---------------------------------------------------------------------------
__global__ __launch_bounds__(256)
void norm_gate_k(const float* __restrict__ o, const float* __restrict__ rmsw,
                 const unsigned short* __restrict__ sg,
                 unsigned short* __restrict__ ob) {
  const int t = threadIdx.x;
  const int w = t >> 6, lane = t & 63;
  const int grp = blockIdx.x * 4 + w;   // 0..8191
  const int row = grp >> 2, h = grp & 3;
  const size_t base = (size_t)row * 1024 + h * 256 + lane * 4;
  vf4 val = *(const vf4*)(o + base);
  float ss = val.x * val.x + val.y * val.y + val.z * val.z + val.w * val.w;
#pragma unroll
  for (int mm = 1; mm < 64; mm <<= 1) ss += __shfl_xor(ss, mm, 64);
  const float scale = rsqrtf(ss * (1.f / 256.f) + 1e-5f);
  us4 sgv = *(const us4*)(sg + base);
  vf4 rw = *(const vf4*)(rmsw + lane * 4);
  us4 outv;
  outv.x = f2bf(val.x * scale * rw.x * bf2f((unsigned int)sgv.x));
  outv.y = f2bf(val.y * scale * rw.y * bf2f((unsigned int)sgv.y));
  outv.z = f2bf(val.z * scale * rw.z * bf2f((unsigned int)sgv.z));
  outv.w = f2bf(val.w * scale * rw.w * bf2f((unsigned int)sgv.w));
  *(us4*)(ob + base) = outv;
}

// ---------------------------------------------------------------------------
// MFMA output GEMM (round-13, unchanged). grid (8,32) = 256 blocks.
// ---------------------------------------------------------------------------
__global__ __launch_bounds__(256)
void out_mfma_k(const unsigned short* __restrict__ Ab,
                const unsigned short* __restrict__ woT, float* __restrict__ Y) {
  __shared__ __align__(16) unsigned short As[64 * 64];
  __shared__ __align__(16) unsigned short Bs[128 * 64];
  const int t = threadIdx.x;
  const int m0 = blockIdx.y << 6;
  const int n0 = blockIdx.x << 7;
  const int w = t >> 6, lane = t & 63;
  const int wm = (w >> 1) * 32, wn = (w & 1) * 64;
  const int qd = lane >> 4, m = lane & 15;
  const int srow = lane >> 3;
  const int scol = ((lane & 7) ^ srow) << 3;

  vf4 acc[2][4];
#pragma unroll
  for (int i = 0; i < 2; ++i)
#pragma unroll
    for (int j = 0; j < 4; ++j) acc[i][j] = vzero();

  for (int k0 = 0; k0 < 1024; k0 += 64) {
    __syncthreads();
#pragma unroll
    for (int cc = 0; cc < 2; ++cc) {
      const int c = (w << 1) + cc;
      const int row = (c << 3) + srow;
      gld16(Ab + (size_t)(m0 + row) * 1024 + k0 + scol, (unsigned short*)As + (c << 9));
    }
#pragma unroll
    for (int cc = 0; cc < 4; ++cc) {
      const int c = (w << 2) + cc;
      const int row = (c << 3) + srow;
      gld16(woT + (size_t)(n0 + row) * 1024 + k0 + scol, (unsigned short*)Bs + (c << 9));
    }
    __syncthreads();
#pragma unroll
    for (int ks = 0; ks < 2; ++ks) {
      const int sw = (((ks << 2) + qd) ^ (m & 7)) << 3;
      short8 af[2], bf[4];
#pragma unroll
      for (int i = 0; i < 2; ++i)
        af[i] = *(const short8*)&As[(wm + i * 16 + m) * 64 + sw];
#pragma unroll
      for (int j = 0; j < 4; ++j)
        bf[j] = *(const short8*)&Bs[(wn + j * 16 + m) * 64 + sw];
#pragma unroll
      for (int i = 0; i < 2; ++i)
#pragma unroll
        for (int j = 0; j < 4; ++j)
          acc[i][j] = __builtin_amdgcn_mfma_f32_16x16x32_bf16(af[i], bf[j], acc[i][j], 0, 0, 0);
    }
  }
#pragma unroll
  for (int i = 0; i < 2; ++i)
#pragma unroll
    for (int j = 0; j < 4; ++j)
#pragma unroll
      for (int r = 0; r < 4; ++r) {
        const int grow = m0 + wm + i * 16 + qd * 4 + r;
        const int gcol = n0 + wn + j * 16 + m;
        Y[(size_t)grow * 1024 + gcol] = acc[i][j][r];
      }
}

// ---------------------------------------------------------------------------
extern "C" void kernel_launch(void* const* d_in, const int* in_sizes, int n_in,
                              void* d_out, int out_size, void* d_ws, size_t ws_size,
                              hipStream_t stream) {
  const float* x    = (const float*)d_in[0];
  const float* Wq   = (const float*)d_in[1];
  const float* Wk   = (const float*)d_in[2];
  const float* Wv   = (const float*)d_in[3];
  const float* Wg   = (const float*)d_in[4];
  const float* Wgk1 = (const float*)d_in[5];
  const float* Wgk2 = (const float*)d_in[6];
  const float* bgk2 = (const float*)d_in[7];
  const float* Wout = (const float*)d_in[8];
  const float* rmsw = (const float*)d_in[9];

  const size_t MB = 1u << 20;
  char* w = (char*)d_ws;
  unsigned short* qb16   = (unsigned short*)(w);           // [0,2) MB bf16
  unsigned short* kb16   = (unsigned short*)(w + 2 * MB);  // [2,4)
  unsigned short* vbuf   = (unsigned short*)(w + 4 * MB);  // [4,8)
  unsigned short* sgbuf  = (unsigned short*)(w + 8 * MB);  // [8,12)
  float*          obuf   = (float*)(w + 12 * MB);          // [12,20) fp32
  char*           sreg   = w + 20 * MB;                    // [20,28) multi-phase
  unsigned short* xb     = (unsigned short*)sreg;          //   phase 0: 4 MB
  unsigned short* STbuf  = (unsigned short*)sreg;          //   phase A: 8 MB [v][k]
  unsigned short* obuf_b = (unsigned short*)sreg;          //   phase B: 4 MB
  float*          xlbuf  = (float*)(w + 28 * MB);          // 128 KB
  float*          ebbuf  = (float*)(w + 28 * MB + 131072); // 64 KB
  unsigned short* wqT    = (unsigned short*)(w + 29 * MB); // 1 MB
  unsigned short* wkT    = (unsigned short*)(w + 30 * MB); // 1 MB
  unsigned short* wvT    = (unsigned short*)(w + 31 * MB); // 2 MB
  unsigned short* wgT    = (unsigned short*)(w + 33 * MB); // 2 MB
  unsigned short* woT    = (unsigned short*)(w + 35 * MB); // 2 MB

  wtrans_k<<<512, 256, 0, stream>>>(Wq, Wk, Wv, Wg, Wout, wqT, wkT, wvT, wgT, woT);
  xcvt_lr_k<<<1024, 256, 0, stream>>>(x, Wgk1, xb, xlbuf);
  proj_mfma_k<<<dim3(24, 16), 256, 0, stream>>>(xb, wqT, wkT, wvT, wgT, qb16, kb16, vbuf, sgbuf);
  gate_scan_k<<<256, 256, 0, stream>>>(xlbuf, Wgk2, bgk2, qb16, kb16, ebbuf);
  intra_kv_k<<<dim3(2, 16, 8), 256, 0, stream>>>(qb16, kb16, vbuf, obuf, STbuf);
  state_scan_k<<<128, 256, 0, stream>>>(STbuf, ebbuf);
  o_inter_k<<<dim3(2, 16, 8), 256, 0, stream>>>(qb16, STbuf, obuf);
  norm_gate_k<<<2048, 256, 0, stream>>>(obuf, rmsw, sgbuf, obuf_b);
  out_mfma_k<<<dim3(8, 32), 256, 0, stream>>>(obuf_b, woT, (float*)d_out);
}

// Round 5
// 186.488 us; speedup vs baseline: 1.7448x; 1.0425x over previous
//
#include <hip/hip_runtime.h>
#include <math.h>

// GLA: B=2, N=1024, D=1024, H=4, KD=512, VD=1024, DK=128, DV=256, LR=16
// Round 17: single change vs round 16 — state_scan_v2:
//   2 elements/thread (131072 threads, 8 waves/CU vs old 2) with ALL 16 ST
//   chunk loads + 16 decay loads preloaded into registers (48-deep MLP),
//   then register-only serial carry + coalesced 4B stores.
//   Per-element math order identical to old kernel -> bit-identical output.
// Everything else byte-identical to round 16 (194.4 us).

typedef __attribute__((ext_vector_type(4))) float vf4;
typedef __attribute__((ext_vector_type(2))) float vf2;
typedef __attribute__((ext_vector_type(4))) unsigned int vu4;
typedef __attribute__((ext_vector_type(8))) short short8;
typedef __attribute__((ext_vector_type(4))) unsigned short us4;

#define DEVI static __device__ __forceinline__
DEVI vf4 vzero() { vf4 x = {0.f, 0.f, 0.f, 0.f}; return x; }

DEVI float bf2f(unsigned int u) {
  union { unsigned int i; float f; } c; c.i = u << 16; return c.f;
}
DEVI unsigned short f2bf(float f) {
  union { float f; unsigned int i; } c; c.f = f;
  unsigned int i = c.i;
  return (unsigned short)((i + 0x7fffu + ((i >> 16) & 1u)) >> 16);
}
DEVI void unpack8(vu4 r, float* f) {
  f[0] = bf2f(r.x & 0xffffu); f[1] = bf2f(r.x >> 16);
  f[2] = bf2f(r.y & 0xffffu); f[3] = bf2f(r.y >> 16);
  f[4] = bf2f(r.z & 0xffffu); f[5] = bf2f(r.z >> 16);
  f[6] = bf2f(r.w & 0xffffu); f[7] = bf2f(r.w >> 16);
}
DEVI vu4 pack8(const float* f) {
  vu4 o;
  o.x = (unsigned int)f2bf(f[0]) | ((unsigned int)f2bf(f[1]) << 16);
  o.y = (unsigned int)f2bf(f[2]) | ((unsigned int)f2bf(f[3]) << 16);
  o.z = (unsigned int)f2bf(f[4]) | ((unsigned int)f2bf(f[5]) << 16);
  o.w = (unsigned int)f2bf(f[6]) | ((unsigned int)f2bf(f[7]) << 16);
  return o;
}

DEVI void gld16(const unsigned short* g, unsigned short* l) {
  __builtin_amdgcn_global_load_lds(
      (const __attribute__((address_space(1))) unsigned int*)g,
      (__attribute__((address_space(3))) unsigned int*)l,
      16, 0, 0);
}

// ---------------------------------------------------------------------------
// wtrans_k: weight transpose + fp32->bf16. 2 tiles (64x64) per block,
// loads all issued before the single sync. grid 512 x 256.
// ---------------------------------------------------------------------------
__global__ __launch_bounds__(256)
void wtrans_k(const float* __restrict__ Wq, const float* __restrict__ Wk,
              const float* __restrict__ Wv, const float* __restrict__ Wg,
              const float* __restrict__ Wo,
              unsigned short* __restrict__ wqT, unsigned short* __restrict__ wkT,
              unsigned short* __restrict__ wvT, unsigned short* __restrict__ wgT,
              unsigned short* __restrict__ woT) {
  __shared__ float T[2][64][65];
  const int t = threadIdx.x;
  const int r = t >> 2, s = t & 3;
  float f[2][16];
  const float* srcs[2];
  unsigned short* dsts[2];
#pragma unroll
  for (int i = 0; i < 2; ++i) {
    const int tid = blockIdx.x * 2 + i;   // 0..1023
    const float* W; unsigned short* O; int kt, cb, N;
    if (tid < 128)       { W = Wq; O = wqT; N = 512;  kt = tid >> 3;          cb = tid & 7;  }
    else if (tid < 256)  { W = Wk; O = wkT; N = 512;  kt = (tid - 128) >> 3;  cb = tid & 7;  }
    else if (tid < 512)  { W = Wv; O = wvT; N = 1024; kt = (tid - 256) >> 4;  cb = tid & 15; }
    else if (tid < 768)  { W = Wg; O = wgT; N = 1024; kt = (tid - 512) >> 4;  cb = tid & 15; }
    else                 { W = Wo; O = woT; N = 1024; kt = (tid - 768) >> 4;  cb = tid & 15; }
    srcs[i] = W + (size_t)(kt * 64 + r) * N + cb * 64 + s * 16;
    dsts[i] = O + (size_t)(cb * 64 + r) * 1024 + kt * 64 + s * 16;
  }
  // issue all 8 vector loads up-front (both tiles)
#pragma unroll
  for (int i = 0; i < 2; ++i)
#pragma unroll
    for (int u = 0; u < 4; ++u)
      *(vf4*)&f[i][u * 4] = *(const vf4*)(srcs[i] + u * 4);
  // LDS writes (bank: (r + col) & 31, 2-way = free)
#pragma unroll
  for (int i = 0; i < 2; ++i)
#pragma unroll
    for (int u = 0; u < 16; ++u)
      T[i][r][s * 16 + u] = f[i][u];
  __syncthreads();
  // transposed read (role swap: r = n-local, s = k-group), cvt, store
#pragma unroll
  for (int i = 0; i < 2; ++i) {
    unsigned int pk[8];
#pragma unroll
    for (int u = 0; u < 8; ++u) {
      unsigned int lo = f2bf(T[i][s * 16 + 2 * u][r]);
      unsigned int hi = f2bf(T[i][s * 16 + 2 * u + 1][r]);
      pk[u] = lo | (hi << 16);
    }
    *(vu4*)dsts[i] = *(vu4*)&pk[0];
    *(vu4*)(dsts[i] + 8) = *(vu4*)&pk[4];
  }
}

// ---------------------------------------------------------------------------
// xcvt_lr_k: bid<512 -> x fp32->bf16 flat streaming; bid>=512 -> lowrank.
// grid 1024 x 256.
// ---------------------------------------------------------------------------
__global__ __launch_bounds__(256)
void xcvt_lr_k(const float* __restrict__ X, const float* __restrict__ Wgk1,
               unsigned short* __restrict__ xb, float* __restrict__ xl) {
  const int bid = blockIdx.x, t = threadIdx.x;
  if (bid < 512) {  // ---- x convert: 512*256*16 = 2M elements, 64B/lane
    const size_t base = (size_t)bid * 4096 + t * 16;
    float f[16];
    *(vf4*)&f[0]  = *(const vf4*)(X + base);
    *(vf4*)&f[4]  = *(const vf4*)(X + base + 4);
    *(vf4*)&f[8]  = *(const vf4*)(X + base + 8);
    *(vf4*)&f[12] = *(const vf4*)(X + base + 12);
    *(vu4*)(xb + base) = pack8(f);
    *(vu4*)(xb + base + 8) = pack8(f + 8);
    return;
  }
  // ---- lowrank: xl = x @ Wgk1, one wave per row
  const int w = t >> 6, lane = t & 63;
  const int row = (bid - 512) * 4 + w;
  float acc[16];
#pragma unroll
  for (int c2 = 0; c2 < 16; ++c2) acc[c2] = 0.f;
  const float* xp = X + (size_t)row * 1024 + lane * 16;
  float xv[16];
#pragma unroll
  for (int u = 0; u < 4; ++u)
    *(vf4*)&xv[u * 4] = *(const vf4*)(xp + u * 4);
#pragma unroll
  for (int j = 0; j < 16; ++j) {
    const float* wp = Wgk1 + (size_t)(lane * 16 + j) * 16;
    float wv[16];
#pragma unroll
    for (int u = 0; u < 4; ++u)
      *(vf4*)&wv[u * 4] = *(const vf4*)(wp + u * 4);
#pragma unroll
    for (int c2 = 0; c2 < 16; ++c2) acc[c2] = fmaf(xv[j], wv[c2], acc[c2]);
  }
#pragma unroll
  for (int mm = 1; mm < 64; mm <<= 1) {
#pragma unroll
    for (int c2 = 0; c2 < 16; ++c2) acc[c2] += __shfl_xor(acc[c2], mm, 64);
  }
  if (lane == 0) {
#pragma unroll
    for (int c2 = 0; c2 < 16; ++c2) xl[(size_t)row * 16 + c2] = acc[c2];
  }
}

// ---------------------------------------------------------------------------
// MFMA projection (round-13, unchanged). grid (24,16) = 384 blocks.
// ---------------------------------------------------------------------------
__global__ __launch_bounds__(256)
void proj_mfma_k(const unsigned short* __restrict__ xb,
                 const unsigned short* __restrict__ wqT, const unsigned short* __restrict__ wkT,
                 const unsigned short* __restrict__ wvT, const unsigned short* __restrict__ wgT,
                 unsigned short* __restrict__ qb, unsigned short* __restrict__ kb,
                 unsigned short* __restrict__ vb, unsigned short* __restrict__ sgb) {
  __shared__ __align__(16) unsigned short As[128 * 64];
  __shared__ __align__(16) unsigned short Bs[128 * 64];
  const int t = threadIdx.x;
  const int m0 = blockIdx.y << 7;
  const int nt = blockIdx.x;
  const unsigned short* WT; int n0; int kind;
  if (nt < 4)       { WT = wqT; n0 = nt << 7;        kind = 0; }
  else if (nt < 8)  { WT = wkT; n0 = (nt - 4) << 7;  kind = 1; }
  else if (nt < 16) { WT = wvT; n0 = (nt - 8) << 7;  kind = 2; }
  else              { WT = wgT; n0 = (nt - 16) << 7; kind = 3; }

  const int w = t >> 6, lane = t & 63;
  const int wm = (w >> 1) << 6, wn = (w & 1) << 6;
  const int qd = lane >> 4, m = lane & 15;
  const int srow = lane >> 3;
  const int scol = ((lane & 7) ^ srow) << 3;

  vf4 acc[4][4];
#pragma unroll
  for (int i = 0; i < 4; ++i)
#pragma unroll
    for (int j = 0; j < 4; ++j) acc[i][j] = vzero();

  for (int k0 = 0; k0 < 1024; k0 += 64) {
    __syncthreads();
#pragma unroll
    for (int cc = 0; cc < 4; ++cc) {
      const int c = (w << 2) + cc;
      const int row = (c << 3) + srow;
      gld16(xb + (size_t)(m0 + row) * 1024 + k0 + scol, (unsigned short*)As + (c << 9));
      gld16(WT + (size_t)(n0 + row) * 1024 + k0 + scol, (unsigned short*)Bs + (c << 9));
    }
    __syncthreads();
#pragma unroll
    for (int ks = 0; ks < 2; ++ks) {
      const int sw = (((ks << 2) + qd) ^ (m & 7)) << 3;
      short8 af[4], bf[4];
#pragma unroll
      for (int i = 0; i < 4; ++i)
        af[i] = *(const short8*)&As[(wm + i * 16 + m) * 64 + sw];
#pragma unroll
      for (int j = 0; j < 4; ++j)
        bf[j] = *(const short8*)&Bs[(wn + j * 16 + m) * 64 + sw];
#pragma unroll
      for (int i = 0; i < 4; ++i)
#pragma unroll
        for (int j = 0; j < 4; ++j)
          acc[i][j] = __builtin_amdgcn_mfma_f32_16x16x32_bf16(af[i], bf[j], acc[i][j], 0, 0, 0);
    }
  }
#pragma unroll
  for (int i = 0; i < 4; ++i) {
#pragma unroll
    for (int j = 0; j < 4; ++j) {
#pragma unroll
      for (int r = 0; r < 4; ++r) {
        const int grow = m0 + wm + i * 16 + qd * 4 + r;
        const int gcol = n0 + wn + j * 16 + m;
        float val = acc[i][j][r];
        if (kind == 0)      qb[(size_t)grow * 512 + gcol] = f2bf(val);
        else if (kind == 1) kb[(size_t)grow * 512 + gcol] = f2bf(val);
        else if (kind == 2) vb[(size_t)grow * 1024 + gcol] = f2bf(val);
        else {
          val = val / (1.f + expf(-val));
          sgb[(size_t)grow * 1024 + gcol] = f2bf(val);
        }
      }
    }
  }
}

// ---------------------------------------------------------------------------
// gate_scan (round-0): one wave per (b, chunk, 16-kcol group). grid 256 x 256.
// ---------------------------------------------------------------------------
__global__ __launch_bounds__(256)
void gate_scan_k(const float* __restrict__ xl, const float* __restrict__ W2,
                 const float* __restrict__ bias,
                 unsigned short* __restrict__ q, unsigned short* __restrict__ k,
                 float* __restrict__ ebtot) {
  const int t = threadIdx.x;
  const int w = t >> 6, lane = t & 63;
  const int wid = blockIdx.x * 4 + w;     // 0..1023
  const int kt = wid & 31;                // 16-col group
  const int c = (wid >> 5) & 15;
  const int b = wid >> 9;
  const int kbase = kt * 16;
  const size_t rowbase = (size_t)b * 1024 + c * 64;

  const float* xp = xl + (rowbase + lane) * 16;
  float xv[16];
#pragma unroll
  for (int u = 0; u < 4; ++u)
    *(vf4*)&xv[u * 4] = *(const vf4*)(xp + u * 4);

  const size_t a = (rowbase + lane) * 512 + kbase;
  vu4 qr0 = *(const vu4*)(q + a), qr1 = *(const vu4*)(q + a + 8);
  vu4 kr0 = *(const vu4*)(k + a), kr1 = *(const vu4*)(k + a + 8);
  float qf[16], kf[16];
  unpack8(qr0, qf); unpack8(qr1, qf + 8);
  unpack8(kr0, kf); unpack8(kr1, kf + 8);

  float gf[16];
#pragma unroll
  for (int cc = 0; cc < 16; ++cc) {
    const int col = kbase + cc;           // wave-uniform
    float z = bias[col];
#pragma unroll
    for (int j = 0; j < 16; ++j) z = fmaf(xv[j], W2[j * 512 + col], z);
    float ls = fminf(z, 0.f) - log1pf(expf(-fabsf(z)));
    float g = fmaxf(ls * (1.f / 16.f), -3.f);
#pragma unroll
    for (int d = 1; d < 64; d <<= 1) {
      float up = __shfl_up(g, d, 64);
      if (lane >= d) g += up;
    }
    qf[cc] *= expf(g);
    kf[cc] *= expf(fminf(-g, 80.f));
    gf[cc] = g;
  }
  *(vu4*)(q + a) = pack8(qf);
  *(vu4*)(q + a + 8) = pack8(qf + 8);
  *(vu4*)(k + a) = pack8(kf);
  *(vu4*)(k + a + 8) = pack8(kf + 8);
  if (lane == 63) {
    float* ep = ebtot + ((size_t)b * 16 + c) * 512 + kbase;
#pragma unroll
    for (int cc = 0; cc < 16; ++cc) ep[cc] = expf(gf[cc]);
  }
}

// ---------------------------------------------------------------------------
// Fused intra+kv (round-0). grid (vh2, chunk16, bh8) = 256 blocks.
// ---------------------------------------------------------------------------
__global__ __launch_bounds__(256)
void intra_kv_k(const unsigned short* __restrict__ q16, const unsigned short* __restrict__ k16,
                const unsigned short* __restrict__ v, float* __restrict__ o,
                unsigned short* __restrict__ ST) {
  __shared__ __align__(16) unsigned short Qs[64 * 136];
  __shared__ __align__(16) unsigned short Ks[64 * 136];
  __shared__ __align__(16) unsigned short Kt[128 * 68];
  __shared__ __align__(16) unsigned short Vt[128 * 68];
  __shared__ __align__(16) unsigned short Asb[64 * 68];
  const int t = threadIdx.x;
  const int vh = blockIdx.x, c = blockIdx.y, bh = blockIdx.z;
  const int b = bh >> 2, h = bh & 3;
  const size_t rowbase = (size_t)b * 1024 + c * 64;

#pragma unroll
  for (int u2 = 0; u2 < 4; ++u2) {
    const int id = t + (u2 << 8);
    const int row = id >> 4, kg = id & 15;
    vu4 rq = *(const vu4*)(q16 + (rowbase + row) * 512 + h * 128 + kg * 8);
    *(vu4*)&Qs[row * 136 + kg * 8] = rq;
    vu4 rk = *(const vu4*)(k16 + (rowbase + row) * 512 + h * 128 + kg * 8);
    *(vu4*)&Ks[row * 136 + kg * 8] = rk;
    const unsigned short* kp = (const unsigned short*)&rk;
#pragma unroll
    for (int u = 0; u < 8; ++u)
      Kt[(kg * 8 + u) * 68 + row] = kp[u];
    vu4 rv = *(const vu4*)(v + (rowbase + row) * 1024 + h * 256 + vh * 128 + kg * 8);
    const unsigned short* vp = (const unsigned short*)&rv;
#pragma unroll
    for (int u = 0; u < 8; ++u)
      Vt[(kg * 8 + u) * 68 + row] = vp[u];
  }
  __syncthreads();

  const int w = t >> 6, lane = t & 63;
  const int qd = lane >> 4, m = lane & 15;

  // phase 1: A = tril(Q K^T)
  {
    short8 af[4];
#pragma unroll
    for (int kf = 0; kf < 4; ++kf)
      af[kf] = *(const short8*)&Qs[(w * 16 + m) * 136 + kf * 32 + qd * 8];
    vf4 acc[4];
#pragma unroll
    for (int jt = 0; jt < 4; ++jt) acc[jt] = vzero();
#pragma unroll
    for (int jt = 0; jt < 4; ++jt)
#pragma unroll
      for (int kf = 0; kf < 4; ++kf) {
        short8 bfr = *(const short8*)&Ks[(jt * 16 + m) * 136 + kf * 32 + qd * 8];
        acc[jt] = __builtin_amdgcn_mfma_f32_16x16x32_bf16(af[kf], bfr, acc[jt], 0, 0, 0);
      }
#pragma unroll
    for (int jt = 0; jt < 4; ++jt)
#pragma unroll
      for (int r = 0; r < 4; ++r) {
        const int i = w * 16 + qd * 4 + r;
        const int j = jt * 16 + m;
        Asb[i * 68 + j] = f2bf((j <= i) ? acc[jt][r] : 0.f);
      }
  }
  __syncthreads();

  // phase 2: o_intra = A @ V
  {
    vf4 acc2[4][2];
#pragma unroll
    for (int mt = 0; mt < 4; ++mt) { acc2[mt][0] = vzero(); acc2[mt][1] = vzero(); }
#pragma unroll
    for (int kf = 0; kf < 2; ++kf) {
      short8 bf0 = *(const short8*)&Vt[(w * 32 + m) * 68 + kf * 32 + qd * 8];
      short8 bf1 = *(const short8*)&Vt[(w * 32 + 16 + m) * 68 + kf * 32 + qd * 8];
#pragma unroll
      for (int mt = 0; mt < 4; ++mt) {
        short8 af = *(const short8*)&Asb[(mt * 16 + m) * 68 + kf * 32 + qd * 8];
        acc2[mt][0] = __builtin_amdgcn_mfma_f32_16x16x32_bf16(af, bf0, acc2[mt][0], 0, 0, 0);
        acc2[mt][1] = __builtin_amdgcn_mfma_f32_16x16x32_bf16(af, bf1, acc2[mt][1], 0, 0, 0);
      }
    }
#pragma unroll
    for (int mt = 0; mt < 4; ++mt)
#pragma unroll
      for (int nt = 0; nt < 2; ++nt)
#pragma unroll
        for (int r = 0; r < 4; ++r) {
          const int i = mt * 16 + qd * 4 + r;
          const int vc = h * 256 + vh * 128 + w * 32 + nt * 16 + m;
          o[(rowbase + i) * 1024 + vc] = acc2[mt][nt][r];
        }
  }

  // phase 3: ST[v][k] = V^T @ K
  {
    short8 af3[2][2];
#pragma unroll
    for (int mt = 0; mt < 2; ++mt)
#pragma unroll
      for (int kf = 0; kf < 2; ++kf)
        af3[mt][kf] = *(const short8*)&Vt[(w * 32 + mt * 16 + m) * 68 + kf * 32 + qd * 8];
#pragma unroll
    for (int nt = 0; nt < 8; ++nt) {
      vf4 a0 = vzero(), a1 = vzero();
#pragma unroll
      for (int kf = 0; kf < 2; ++kf) {
        short8 bfr = *(const short8*)&Kt[(nt * 16 + m) * 68 + kf * 32 + qd * 8];
        a0 = __builtin_amdgcn_mfma_f32_16x16x32_bf16(af3[0][kf], bfr, a0, 0, 0, 0);
        a1 = __builtin_amdgcn_mfma_f32_16x16x32_bf16(af3[1][kf], bfr, a1, 0, 0, 0);
      }
      const size_t sbase = (size_t)(bh * 16 + c) * 256 + vh * 128 + w * 32;
#pragma unroll
      for (int r = 0; r < 4; ++r) {
        ST[(sbase + qd * 4 + r) * 128 + nt * 16 + m] = f2bf(a0[r]);
        ST[(sbase + 16 + qd * 4 + r) * 128 + nt * 16 + m] = f2bf(a1[r]);
      }
    }
  }
}

// ---------------------------------------------------------------------------
// State scan v2: 2 elements/thread, full register preload (48-deep MLP),
// per-element math order identical to v1. grid 512 x 256.
// ---------------------------------------------------------------------------
__global__ __launch_bounds__(256)
void state_scan_k(unsigned short* __restrict__ ST, const float* __restrict__ ebtot) {
  const int idx = blockIdx.x * 256 + threadIdx.x;  // 0..131071
  const int kgp = idx & 63;                        // k-pair index (2 elems)
  const int vv = (idx >> 6) & 255;
  const int bh = idx >> 14;
  const int b = bh >> 2, h = bh & 3;
  const size_t pbase = (size_t)bh * (16 * 256 * 128) + (size_t)vv * 128 + kgp * 2;
  const size_t ebase = (size_t)b * (16 * 512) + h * 128 + kgp * 2;

  unsigned int stv[16];
  vf2 ebv[16];
#pragma unroll
  for (int c = 0; c < 16; ++c) {
    stv[c] = *(const unsigned int*)(ST + pbase + (size_t)c * 32768);
    ebv[c] = *(const vf2*)(ebtot + ebase + (size_t)c * 512);
  }
  float s0 = 0.f, s1 = 0.f;
#pragma unroll
  for (int c = 0; c < 16; ++c) {
    const float kv0 = bf2f(stv[c] & 0xffffu);
    const float kv1 = bf2f(stv[c] >> 16);
    const unsigned int outw =
        (unsigned int)f2bf(s0) | ((unsigned int)f2bf(s1) << 16);
    *(unsigned int*)(ST + pbase + (size_t)c * 32768) = outw;
    s0 = (s0 + kv0) * ebv[c].x;
    s1 = (s1 + kv1) * ebv[c].y;
  }
}

// ---------------------------------------------------------------------------
// o += Q~ @ S_c via MFMA (round-0). grid (vt2, chunk16, bh8) = 256 blocks.
// ---------------------------------------------------------------------------
__global__ __launch_bounds__(256)
void o_inter_k(const unsigned short* __restrict__ q16, const unsigned short* __restrict__ ST,
               float* __restrict__ o) {
  __shared__ __align__(16) unsigned short Qs[64 * 136];
  __shared__ __align__(16) unsigned short Ss[128 * 136];
  const int t = threadIdx.x;
  const int vt = blockIdx.x, c = blockIdx.y, bh = blockIdx.z;
  const int b = bh >> 2, h = bh & 3;
  const size_t rowbase = (size_t)b * 1024 + c * 64;

#pragma unroll
  for (int u2 = 0; u2 < 4; ++u2) {
    const int id = t + (u2 << 8);
    const int row = id >> 4, kg = id & 15;
    *(vu4*)&Qs[row * 136 + kg * 8] =
        *(const vu4*)(q16 + (rowbase + row) * 512 + h * 128 + kg * 8);
  }
#pragma unroll
  for (int u2 = 0; u2 < 8; ++u2) {
    const int id = t + (u2 << 8);
    const int vrow = id >> 4, kg = id & 15;
    *(vu4*)&Ss[vrow * 136 + kg * 8] =
        *(const vu4*)(ST + ((size_t)(bh * 16 + c) * 256 + vt * 128 + vrow) * 128 + kg * 8);
  }
  __syncthreads();

  const int w = t >> 6, lane = t & 63;
  const int qd = lane >> 4, m = lane & 15;
  short8 af[4];
#pragma unroll
  for (int kf = 0; kf < 4; ++kf)
    af[kf] = *(const short8*)&Qs[(w * 16 + m) * 136 + kf * 32 + qd * 8];
#pragma unroll
  for (int nt = 0; nt < 8; ++nt) {
    vf4 acc = vzero();
#pragma unroll
    for (int kf = 0; kf < 4; ++kf) {
      short8 bfr = *(const short8*)&Ss[(nt * 16 + m) * 136 + kf * 32 + qd * 8];
      acc = __builtin_amdgcn_mfma_f32_16x16x32_bf16(af[kf], bfr, acc, 0, 0, 0);
    }
    float* base = o + (rowbase + w * 16 + qd * 4) * 1024 + h * 256 + vt * 128 + nt * 16 + m;
#pragma unroll
    for (int r = 0; r < 4; ++r)
      base[(size_t)r * 1024] += acc[r];
  }
}

// ---------------------------------------------------------------------------
// RMSNorm over DV=256 + silu-gate (vectorized, wave-per-group). grid 2048.
// ---------------------------------------------------------------------------
__global__ __launch_bounds__(256)
void norm_gate_k(const float* __restrict__ o, const float* __restrict__ rmsw,
                 const unsigned short* __restrict__ sg,
                 unsigned short* __restrict__ ob) {
  const int t = threadIdx.x;
  const int w = t >> 6, lane = t & 63;
  const int grp = blockIdx.x * 4 + w;   // 0..8191
  const int row = grp >> 2, h = grp & 3;
  const size_t base = (size_t)row * 1024 + h * 256 + lane * 4;
  vf4 val = *(const vf4*)(o + base);
  float ss = val.x * val.x + val.y * val.y + val.z * val.z + val.w * val.w;
#pragma unroll
  for (int mm = 1; mm < 64; mm <<= 1) ss += __shfl_xor(ss, mm, 64);
  const float scale = rsqrtf(ss * (1.f / 256.f) + 1e-5f);
  us4 sgv = *(const us4*)(sg + base);
  vf4 rw = *(const vf4*)(rmsw + lane * 4);
  us4 outv;
  outv.x = f2bf(val.x * scale * rw.x * bf2f((unsigned int)sgv.x));
  outv.y = f2bf(val.y * scale * rw.y * bf2f((unsigned int)sgv.y));
  outv.z = f2bf(val.z * scale * rw.z * bf2f((unsigned int)sgv.z));
  outv.w = f2bf(val.w * scale * rw.w * bf2f((unsigned int)sgv.w));
  *(us4*)(ob + base) = outv;
}

// ---------------------------------------------------------------------------
// MFMA output GEMM (round-13, unchanged). grid (8,32) = 256 blocks.
// ---------------------------------------------------------------------------
__global__ __launch_bounds__(256)
void out_mfma_k(const unsigned short* __restrict__ Ab,
                const unsigned short* __restrict__ woT, float* __restrict__ Y) {
  __shared__ __align__(16) unsigned short As[64 * 64];
  __shared__ __align__(16) unsigned short Bs[128 * 64];
  const int t = threadIdx.x;
  const int m0 = blockIdx.y << 6;
  const int n0 = blockIdx.x << 7;
  const int w = t >> 6, lane = t & 63;
  const int wm = (w >> 1) * 32, wn = (w & 1) * 64;
  const int qd = lane >> 4, m = lane & 15;
  const int srow = lane >> 3;
  const int scol = ((lane & 7) ^ srow) << 3;

  vf4 acc[2][4];
#pragma unroll
  for (int i = 0; i < 2; ++i)
#pragma unroll
    for (int j = 0; j < 4; ++j) acc[i][j] = vzero();

  for (int k0 = 0; k0 < 1024; k0 += 64) {
    __syncthreads();
#pragma unroll
    for (int cc = 0; cc < 2; ++cc) {
      const int c = (w << 1) + cc;
      const int row = (c << 3) + srow;
      gld16(Ab + (size_t)(m0 + row) * 1024 + k0 + scol, (unsigned short*)As + (c << 9));
    }
#pragma unroll
    for (int cc = 0; cc < 4; ++cc) {
      const int c = (w << 2) + cc;
      const int row = (c << 3) + srow;
      gld16(woT + (size_t)(n0 + row) * 1024 + k0 + scol, (unsigned short*)Bs + (c << 9));
    }
    __syncthreads();
#pragma unroll
    for (int ks = 0; ks < 2; ++ks) {
      const int sw = (((ks << 2) + qd) ^ (m & 7)) << 3;
      short8 af[2], bf[4];
#pragma unroll
      for (int i = 0; i < 2; ++i)
        af[i] = *(const short8*)&As[(wm + i * 16 + m) * 64 + sw];
#pragma unroll
      for (int j = 0; j < 4; ++j)
        bf[j] = *(const short8*)&Bs[(wn + j * 16 + m) * 64 + sw];
#pragma unroll
      for (int i = 0; i < 2; ++i)
#pragma unroll
        for (int j = 0; j < 4; ++j)
          acc[i][j] = __builtin_amdgcn_mfma_f32_16x16x32_bf16(af[i], bf[j], acc[i][j], 0, 0, 0);
    }
  }
#pragma unroll
  for (int i = 0; i < 2; ++i)
#pragma unroll
    for (int j = 0; j < 4; ++j)
#pragma unroll
      for (int r = 0; r < 4; ++r) {
        const int grow = m0 + wm + i * 16 + qd * 4 + r;
        const int gcol = n0 + wn + j * 16 + m;
        Y[(size_t)grow * 1024 + gcol] = acc[i][j][r];
      }
}

// ---------------------------------------------------------------------------
extern "C" void kernel_launch(void* const* d_in, const int* in_sizes, int n_in,
                              void* d_out, int out_size, void* d_ws, size_t ws_size,
                              hipStream_t stream) {
  const float* x    = (const float*)d_in[0];
  const float* Wq   = (const float*)d_in[1];
  const float* Wk   = (const float*)d_in[2];
  const float* Wv   = (const float*)d_in[3];
  const float* Wg   = (const float*)d_in[4];
  const float* Wgk1 = (const float*)d_in[5];
  const float* Wgk2 = (const float*)d_in[6];
  const float* bgk2 = (const float*)d_in[7];
  const float* Wout = (const float*)d_in[8];
  const float* rmsw = (const float*)d_in[9];

  const size_t MB = 1u << 20;
  char* w = (char*)d_ws;
  unsigned short* qb16   = (unsigned short*)(w);           // [0,2) MB bf16
  unsigned short* kb16   = (unsigned short*)(w + 2 * MB);  // [2,4)
  unsigned short* vbuf   = (unsigned short*)(w + 4 * MB);  // [4,8)
  unsigned short* sgbuf  = (unsigned short*)(w + 8 * MB);  // [8,12)
  float*          obuf   = (float*)(w + 12 * MB);          // [12,20) fp32
  char*           sreg   = w + 20 * MB;                    // [20,28) multi-phase
  unsigned short* xb     = (unsigned short*)sreg;          //   phase 0: 4 MB
  unsigned short* STbuf  = (unsigned short*)sreg;          //   phase A: 8 MB [v][k]
  unsigned short* obuf_b = (unsigned short*)sreg;          //   phase B: 4 MB
  float*          xlbuf  = (float*)(w + 28 * MB);          // 128 KB
  float*          ebbuf  = (float*)(w + 28 * MB + 131072); // 64 KB
  unsigned short* wqT    = (unsigned short*)(w + 29 * MB); // 1 MB
  unsigned short* wkT    = (unsigned short*)(w + 30 * MB); // 1 MB
  unsigned short* wvT    = (unsigned short*)(w + 31 * MB); // 2 MB
  unsigned short* wgT    = (unsigned short*)(w + 33 * MB); // 2 MB
  unsigned short* woT    = (unsigned short*)(w + 35 * MB); // 2 MB

  wtrans_k<<<512, 256, 0, stream>>>(Wq, Wk, Wv, Wg, Wout, wqT, wkT, wvT, wgT, woT);
  xcvt_lr_k<<<1024, 256, 0, stream>>>(x, Wgk1, xb, xlbuf);
  proj_mfma_k<<<dim3(24, 16), 256, 0, stream>>>(xb, wqT, wkT, wvT, wgT, qb16, kb16, vbuf, sgbuf);
  gate_scan_k<<<256, 256, 0, stream>>>(xlbuf, Wgk2, bgk2, qb16, kb16, ebbuf);
  intra_kv_k<<<dim3(2, 16, 8), 256, 0, stream>>>(qb16, kb16, vbuf, obuf, STbuf);
  state_scan_k<<<512, 256, 0, stream>>>(STbuf, ebbuf);
  o_inter_k<<<dim3(2, 16, 8), 256, 0, stream>>>(qb16, STbuf, obuf);
  norm_gate_k<<<2048, 256, 0, stream>>>(obuf, rmsw, sgbuf, obuf_b);
  out_mfma_k<<<dim3(8, 32), 256, 0, stream>>>(obuf_b, woT, (float*)d_out);
}